// Round 1
// baseline (472.345 us; speedup 1.0000x reference)
//
#include <hip/hip_runtime.h>
#include <math.h>

#define ALPHA 0.2f
#define BN_EPS 1e-5f

typedef __attribute__((ext_vector_type(8))) short short8;
typedef __attribute__((ext_vector_type(4))) float v4f;

// ---- bf16 bit helpers (RNE) ----
__device__ __forceinline__ unsigned short f2bf_rne(float f) {
    union { float f; unsigned u; } x; x.f = f;
    unsigned r = x.u + 0x7FFFu + ((x.u >> 16) & 1u);
    return (unsigned short)(r >> 16);
}
__device__ __forceinline__ float bf2f(unsigned short h) {
    union { float f; unsigned u; } x; x.u = ((unsigned)h) << 16;
    return x.f;
}

// ======== prep kernel: pack conv1 weights as MFMA B-fragments (hi/lo bf16) ========
// K-order: k' = ickh*16 + kw (kw 0..15, pad>=11 zero; ickh 0..25, pad 25 zero).
// Kt = k'/32 in [0,13). Fragment slot s = (Nt*13+Kt)*64+lane holds 8 ushorts:
// element j <-> B[k'=Kt*32+(lane>>4)*8+j][oc=Nt*16+(lane&15)].
// hi at ws16[0..13312), lo at ws16[13312..26624).
__global__ __launch_bounds__(256) void prep_kernel(const float* __restrict__ w1,
                                                   unsigned short* __restrict__ ws16) {
    int s = blockIdx.x * 256 + threadIdx.x;
    if (s >= 1664) return;
    int lane = s & 63;
    int ktnt = s >> 6;           // 0..25
    int Kt = ktnt % 13;
    int Nt = ktnt / 13;
    int oc = Nt * 16 + (lane & 15);
    int quad = lane >> 4;
    for (int j = 0; j < 8; ++j) {
        int kp = Kt * 32 + quad * 8 + j;
        int kw = kp & 15, ickh = kp >> 4;
        float w = 0.f;
        if (kw < 11 && ickh < 25) w = w1[oc * 275 + ickh * 11 + kw];
        unsigned short h = f2bf_rne(w);
        ws16[s * 8 + j] = h;
        ws16[13312 + s * 8 + j] = f2bf_rne(w - bf2f(h));
    }
}

// ======== main kernel ========
// LDS (floats): per-item stride IT=4648 (%32==8):
//   [0,2112)    : xh [5][5][25]x2half=1250 (ph 0-1), then aT [2][32][33] (ph 2+)
//   [2112,3776) : ph 0.5-1: conv1 A-panels abf (dwords [2112,3956), 1844/item:
//                 per-item region R2=half*25+ickh (50 regions x 36 dwords) +
//                 44 zero slack at [1800,1844) for padded-K overflow reads);
//                 ph 1-epilogue onward: h1 [2][32][26] (h2 aliases, ph 6+)
//   [3776,4640) : abf tail (ph 0.5-1), then p1 [half*432+ic*13+j] (ph 4+),
//                 p2f[384] aliases ph 9+
// cst @9296 [4][32].  Total 9424 floats = 36.8 KB -> 4 blocks/CU.
// NOTE: abf aliases h1 -> a __syncthreads() separates the MFMA loop (abf reads)
// from the h1 epilogue stores.
#define IT 4648
#define H1O 2112
#define P1O 3776
#define CSTO 9296
#define LDS_TOTAL (9296 + 128)
#define ABF_PER_IT 1844

__global__ __launch_bounds__(256, 4) void gcn_kernel(
    const float* __restrict__ x,
    const float* __restrict__ w1, const float* __restrict__ b1,
    const float* __restrict__ g1, const float* __restrict__ be1,
    const float* __restrict__ mu1, const float* __restrict__ va1,
    const float* __restrict__ w2, const float* __restrict__ b2,
    const float* __restrict__ g2, const float* __restrict__ be2,
    const float* __restrict__ mu2, const float* __restrict__ va2,
    const float* __restrict__ lw, const float* __restrict__ lb,
    const unsigned short* __restrict__ ws16,
    float* __restrict__ out)
{
    __shared__ float lds[LDS_TOTAL];
    float* cst = lds + CSTO;

    const int tid = threadIdx.x;
    const int b0  = blockIdx.x * 2;

    // ---- phase 0: load 2 items as float2, remap into xh; BN consts ----
    {
        const float2* xg2 = (const float2*)(x + (size_t)b0 * 1250);
        for (int i2 = tid; i2 < 1250; i2 += 256) {
            float2 v = xg2[i2];
            int i = 2 * i2;
            int it = (i >= 1250) ? 1 : 0;
            int j = i - it * 1250;
            int c = j / 250; int r = j - c * 250;
            int h = r / 50;  int w50 = r - h * 50;
            int ha = (w50 >= 25) ? 1 : 0;
            lds[it * IT + ((ha * 5 + c) * 5 + h) * 25 + (w50 - ha * 25)] = v.x;
            int w51 = w50 + 1;
            int hb = (w51 >= 25) ? 1 : 0;
            lds[it * IT + ((hb * 5 + c) * 5 + h) * 25 + (w51 - hb * 25)] = v.y;
        }
    }
    if (tid < 64) {
        int oc = tid & 31;
        if (tid < 32) {
            float inv = g1[oc] * rsqrtf(va1[oc] + BN_EPS);
            cst[oc]      = inv;
            cst[32 + oc] = be1[oc] - mu1[oc] * inv;
        } else {
            float inv = g2[oc] * rsqrtf(va2[oc] + BN_EPS);
            cst[64 + oc] = inv;
            cst[96 + oc] = be2[oc] - mu2[oc] * inv;
        }
    }
    __syncthreads();

    // ---- phase 0.5: stage bf16-RNE A panels (2 parity copies + halo) ----
    // Per-item abf lives at dword offset it*IT + H1O (aliases the h1/p1 space,
    // which is only written after phase 1). d2 in [1800,1844) is zero slack.
    {
        unsigned* abf0 = (unsigned*)lds;
        for (int d = tid; d < 2 * ABF_PER_IT; d += 256) {
            int it = (d >= ABF_PER_IT) ? 1 : 0;
            int d2 = d - it * ABF_PER_IT;
            unsigned u = 0;
            if (d2 < 1800) {
                int R2 = d2 / 36, o = d2 - R2 * 36;
                int cp = (o >= 18) ? 1 : 0;
                int half = (R2 >= 25) ? 1 : 0;
                int ickh = R2 - half * 25;
                int e = 2 * o - (cp ? 37 : 0);
                const float* src = &lds[it * IT + (half * 25 + ickh) * 25];
                int p0 = e + 20; if (p0 >= 25) p0 -= 25; if (p0 >= 25) p0 -= 25;
                int p1 = e + 21; if (p1 >= 25) p1 -= 25; if (p1 >= 25) p1 -= 25;
                u = (unsigned)f2bf_rne(src[p0]) | ((unsigned)f2bf_rne(src[p1]) << 16);
            }
            abf0[it * IT + H1O + d2] = u;
        }
    }
    __syncthreads();

    // ---- phase 1: conv1 via MFMA 16x16x32 bf16 (A bf16-RNE, B=hi+lo) ----
    // wave -> (item = w>>1, M-tile pair = (w&1)*2); M rows: m=half*25+pos (<50).
    {
        const int wave = tid >> 6, lane = tid & 63;
        const int it = wave >> 1;
        const int Mtb = (wave & 1) * 2;
        const int quad = lane >> 4, m16 = lane & 15;
        const int kw0 = (quad & 1) * 8;
        const int ickh0 = quad >> 1;
        const unsigned* abf = (const unsigned*)lds;   // dword-indexed

        int dwb[2];
#pragma unroll
        for (int mt = 0; mt < 2; ++mt) {
            int mg = (Mtb + mt) * 16 + m16;
            int half = (mg >= 25) ? 1 : 0;
            int pos = mg - half * 25; pos = (pos > 24) ? 24 : pos;  // pad rows clamp
            int e0 = pos + kw0;
            int c = e0 & 1;
            int R2b = half * 25 + ickh0;
            dwb[mt] = it * IT + H1O + R2b * 36 + c * 18 + ((e0 + c) >> 1);
        }

        v4f zz = {0.f, 0.f, 0.f, 0.f};
        v4f acc[2][2];
        acc[0][0] = zz; acc[0][1] = zz; acc[1][0] = zz; acc[1][1] = zz;

        for (int Kt = 0; Kt < 13; ++Kt) {
            union { unsigned u[4]; short8 v; } af[2];
#pragma unroll
            for (int mt = 0; mt < 2; ++mt) {
                int base = dwb[mt] + Kt * 72;   // R2 advances by 2 per Kt
                af[mt].u[0] = abf[base + 0];
                af[mt].u[1] = abf[base + 1];
                af[mt].u[2] = abf[base + 2];
                af[mt].u[3] = abf[base + 3];
            }
#pragma unroll
            for (int nt = 0; nt < 2; ++nt) {
                const short8* ph = (const short8*)(ws16 + ((nt * 13 + Kt) * 64 + lane) * 8);
                const short8* pl = (const short8*)(ws16 + 13312 + ((nt * 13 + Kt) * 64 + lane) * 8);
                short8 bh = *ph;
                short8 bl = *pl;
#pragma unroll
                for (int mt = 0; mt < 2; ++mt) {
                    acc[mt][nt] = __builtin_amdgcn_mfma_f32_16x16x32_bf16(af[mt].v, bh, acc[mt][nt], 0, 0, 0);
                    acc[mt][nt] = __builtin_amdgcn_mfma_f32_16x16x32_bf16(af[mt].v, bl, acc[mt][nt], 0, 0, 0);
                }
            }
        }

        // abf (aliased with h1) is dead only once ALL waves finished their MFMAs
        __syncthreads();

        // epilogue: D col=lane&15 (oc within tile), row=quad*4+r; add bias, store h1
        float bias0 = b1[m16], bias1 = b1[16 + m16];
        float* hdst = &lds[it * IT + H1O];
#pragma unroll
        for (int mt = 0; mt < 2; ++mt) {
#pragma unroll
            for (int r = 0; r < 4; ++r) {
                int mg = (Mtb + mt) * 16 + quad * 4 + r;
                if (mg < 50) {
                    int half = (mg >= 25) ? 1 : 0;
                    int pos = mg - half * 25;
                    hdst[(half * 32 + m16) * 26 + pos]      = acc[mt][0][r] + bias0;
                    hdst[(half * 32 + 16 + m16) * 26 + pos] = acc[mt][1][r] + bias1;
                }
            }
        }
    }
    __syncthreads();

    // ---- phase 2: scores a[n][m]=<h1[n],h1[m]>, leaky -> aT[m][n] (over xh) ----
    {
        int n = tid & 31, grp = tid >> 5;
        int it = grp >> 2, mq = grp & 3;
        const float* H = &lds[it * IT + H1O];
        float* A = &lds[it * IT];
#pragma unroll
        for (int half = 0; half < 2; ++half) {
            float pn[25];
            const float* bp = &H[(half * 32 + n) * 26];
            const float2* bp2 = (const float2*)bp;
#pragma unroll
            for (int f2 = 0; f2 < 12; ++f2) {
                float2 v = bp2[f2];
                pn[2 * f2] = v.x; pn[2 * f2 + 1] = v.y;
            }
            pn[24] = bp[24];
#pragma unroll
            for (int i = 0; i < 8; ++i) {
                int m = mq * 8 + i;
                const float* pm = &H[(half * 32 + m) * 26];
                const float2* pm2 = (const float2*)pm;
                float s = 0.f;
#pragma unroll
                for (int f2 = 0; f2 < 12; ++f2) {
                    float2 v = pm2[f2];
                    s += pn[2 * f2] * v.x + pn[2 * f2 + 1] * v.y;
                }
                s += pn[24] * pm[24];
                s = (s > 0.f) ? s : ALPHA * s;
                A[(half * 32 + m) * 33 + n] = s;
            }
        }
    }
    __syncthreads();

    // ---- phase 3: softmax over n; 128 rows x 2 lanes ----
    {
        int row = tid >> 1, q = tid & 1;
        int it = row >> 6, rm = row & 63;
        float* rp = &lds[it * IT + rm * 33];
        float ev[16];
        float mx = -INFINITY;
#pragma unroll
        for (int k = 0; k < 16; ++k) { ev[k] = rp[q + 2 * k]; mx = fmaxf(mx, ev[k]); }
        mx = fmaxf(mx, __shfl_xor(mx, 1));
        float s = 0.f;
#pragma unroll
        for (int k = 0; k < 16; ++k) { ev[k] = __expf(ev[k] - mx); s += ev[k]; }
        s += __shfl_xor(s, 1);
        float inv = 1.f / s;
#pragma unroll
        for (int k = 0; k < 16; ++k) rp[q + 2 * k] = ev[k] * inv;
    }
    __syncthreads();

    // ---- phase 4+5: (att @ h1) -> bn1 -> maxpool2 -> relu -> p1 ----
    for (int e = tid; e < 1536; e += 256) {
        int it = (e >= 768) ? 1 : 0;
        int r = e - it * 768;
        int half = (r >= 384) ? 1 : 0;
        int r2 = r - half * 384;
        int n = r2 / 12, j = r2 - n * 12;
        const float* A = &lds[it * IT + half * 1056 + n];
        const float2* hv2 = (const float2*)&lds[it * IT + H1O + half * 832 + 2 * j];
        float s0 = 0.f, s1 = 0.f;
#pragma unroll
        for (int m = 0; m < 32; ++m) {
            float a = A[m * 33];
            float2 v = hv2[m * 13];
            s0 += a * v.x;
            s1 += a * v.y;
        }
        float inv = cst[n], sh = cst[32 + n];
        float v0 = s0 * inv + sh, v1 = s1 * inv + sh;
        lds[it * IT + P1O + half * 432 + n * 13 + j] = fmaxf(fmaxf(v0, v1), 0.f);
    }
    __syncthreads();

    // ---- phase 6: conv2 (circular pad 2, K=160) -> h2 (over h1) ----
    {
        int wave = tid >> 6, lane = tid & 63;
        int oc0 = __builtin_amdgcn_readfirstlane(wave * 8);
        int l = (lane < 48) ? lane : 0;
        int it = (l >= 24) ? 1 : 0;
        int r = l - it * 24;
        int half = (r >= 12) ? 1 : 0;
        int ow = r - half * 12;
        const float* pbase = &lds[it * IT + P1O + half * 432];
        float* hout = &lds[it * IT + H1O + half * 432];
        int jj[5];
#pragma unroll
        for (int kw = 0; kw < 5; ++kw) {
            int p = ow + kw - 2;
            if (p < 0) p += 12;
            if (p >= 12) p -= 12;
            jj[kw] = p;
        }
        float acc[8];
#pragma unroll
        for (int o = 0; o < 8; ++o) acc[o] = 0.f;
        for (int ic = 0; ic < 32; ++ic) {
            const float* pp = pbase + ic * 13;
            const float* wp = w2 + oc0 * 160 + ic * 5;
#pragma unroll
            for (int kw = 0; kw < 5; ++kw) {
                float pv = pp[jj[kw]];
#pragma unroll
                for (int o = 0; o < 8; ++o) acc[o] += pv * wp[o * 160 + kw];
            }
        }
        if (lane < 48) {
#pragma unroll
            for (int o = 0; o < 8; ++o)
                hout[(oc0 + o) * 13 + ow] = acc[o] + b2[oc0 + o];
        }
    }
    __syncthreads();

    // ---- phase 7: layer-2 scores ----
    {
        int n = tid & 31, grp = tid >> 5;
        int it = grp >> 2, mq = grp & 3;
        const float* H = &lds[it * IT + H1O];
        float* A = &lds[it * IT];
#pragma unroll
        for (int half = 0; half < 2; ++half) {
            float pn[12];
            const float* bp = &H[half * 432 + n * 13];
#pragma unroll
            for (int f = 0; f < 12; ++f) pn[f] = bp[f];
#pragma unroll
            for (int i = 0; i < 8; ++i) {
                int m = mq * 8 + i;
                const float* pm = &H[(1 - half) * 432 + m * 13];
                float s = 0.f;
#pragma unroll
                for (int f = 0; f < 12; ++f) s += pn[f] * pm[f];
                s = (s > 0.f) ? s : ALPHA * s;
                A[(half * 32 + m) * 33 + n] = s;
            }
        }
    }
    __syncthreads();

    // ---- phase 8: softmax ----
    {
        int row = tid >> 1, q = tid & 1;
        int it = row >> 6, rm = row & 63;
        float* rp = &lds[it * IT + rm * 33];
        float ev[16];
        float mx = -INFINITY;
#pragma unroll
        for (int k = 0; k < 16; ++k) { ev[k] = rp[q + 2 * k]; mx = fmaxf(mx, ev[k]); }
        mx = fmaxf(mx, __shfl_xor(mx, 1));
        float s = 0.f;
#pragma unroll
        for (int k = 0; k < 16; ++k) { ev[k] = __expf(ev[k] - mx); s += ev[k]; }
        s += __shfl_xor(s, 1);
        float inv = 1.f / s;
#pragma unroll
        for (int k = 0; k < 16; ++k) rp[q + 2 * k] = ev[k] * inv;
    }
    __syncthreads();

    // ---- phase 9+10: (att2 @ h2) -> bn2 -> pool -> relu -> p2f (over p1) ----
    for (int e = tid; e < 768; e += 256) {
        int it = (e >= 384) ? 1 : 0;
        int r = e - it * 384;
        int n = r / 12; int rem = r - n * 12;
        int half = (rem >= 6) ? 1 : 0;
        int j = rem - half * 6;
        const float* A  = &lds[it * IT + half * 1056 + n];
        const float* hv = &lds[it * IT + H1O + half * 432 + 2 * j];
        float s0 = 0.f, s1 = 0.f;
#pragma unroll
        for (int m = 0; m < 32; ++m) {
            float a = A[m * 33];
            s0 += a * hv[m * 13];
            s1 += a * hv[m * 13 + 1];
        }
        float inv = cst[64 + n], sh = cst[96 + n];
        lds[it * IT + P1O + r] = fmaxf(fmaxf(s0 * inv + sh, s1 * inv + sh), 0.f);
    }
    __syncthreads();

    // ---- phase 11: linear 384 -> 13, both items; float4 dot ----
    if (tid < 208) {
        int s8 = tid & 7;
        int rest = tid >> 3;
        int it = (rest >= 13) ? 1 : 0;
        int o = rest - it * 13;
        const float4* wv4 = (const float4*)(lw + o * 384 + s8 * 48);
        const float4* fv4 = (const float4*)&lds[it * IT + P1O + s8 * 48];
        float s = 0.f;
#pragma unroll
        for (int i = 0; i < 12; ++i) {
            float4 w4 = wv4[i];
            float4 f4 = fv4[i];
            s += f4.x * w4.x + f4.y * w4.y + f4.z * w4.z + f4.w * w4.w;
        }
        s += __shfl_down(s, 4, 8);
        s += __shfl_down(s, 2, 8);
        s += __shfl_down(s, 1, 8);
        if (s8 == 0) out[(size_t)(b0 + it) * 13 + o] = s + lb[o];
    }
}

extern "C" void kernel_launch(void* const* d_in, const int* in_sizes, int n_in,
                              void* d_out, int out_size, void* d_ws, size_t ws_size,
                              hipStream_t stream) {
    const float* x   = (const float*)d_in[0];
    const float* w1  = (const float*)d_in[1];
    const float* b1  = (const float*)d_in[2];
    const float* g1  = (const float*)d_in[3];
    const float* be1 = (const float*)d_in[4];
    const float* mu1 = (const float*)d_in[5];
    const float* va1 = (const float*)d_in[6];
    const float* w2  = (const float*)d_in[7];
    const float* b2  = (const float*)d_in[8];
    const float* g2  = (const float*)d_in[9];
    const float* be2 = (const float*)d_in[10];
    const float* mu2 = (const float*)d_in[11];
    const float* va2 = (const float*)d_in[12];
    const float* lw  = (const float*)d_in[13];
    const float* lb  = (const float*)d_in[14];
    float* out = (float*)d_out;
    unsigned short* ws16 = (unsigned short*)d_ws;

    // pack conv1 weights into MFMA B-fragments (hi/lo bf16), 53 KB in d_ws
    prep_kernel<<<7, 256, 0, stream>>>(w1, ws16);

    int B = in_sizes[0] / 1250;  // 16384
    gcn_kernel<<<B / 2, 256, 0, stream>>>(x, w1, b1, g1, be1, mu1, va1,
                                          w2, b2, g2, be2, mu2, va2, lw, lb,
                                          ws16, out);
}

// Round 2
// 460.012 us; speedup vs baseline: 1.0268x; 1.0268x over previous
//
#include <hip/hip_runtime.h>
#include <math.h>

#define ALPHA 0.2f
#define BN_EPS 1e-5f

typedef __attribute__((ext_vector_type(8))) short short8;
typedef __attribute__((ext_vector_type(4))) float v4f;

// ---- bf16 bit helpers (RNE) ----
__device__ __forceinline__ unsigned short f2bf_rne(float f) {
    union { float f; unsigned u; } x; x.f = f;
    unsigned r = x.u + 0x7FFFu + ((x.u >> 16) & 1u);
    return (unsigned short)(r >> 16);
}
__device__ __forceinline__ float bf2f(unsigned short h) {
    union { float f; unsigned u; } x; x.u = ((unsigned)h) << 16;
    return x.f;
}

// ======== prep kernel: pack conv1 + conv2 weights as MFMA B-fragments ========
// conv1: K-order k' = ickh*16 + kw (kw 0..15, pad>=11 zero; ickh 0..25, pad 25 zero).
//   Kt = k'/32 in [0,13). Slot s = (Nt*13+Kt)*64+lane holds 8 ushorts:
//   elem j <-> B[k'=Kt*32+(lane>>4)*8+j][oc=Nt*16+(lane&15)].
//   hi at ws16[0..13312), lo at ws16[13312..26624).
// conv2: K-order k = ic*5 + kw, K=160 = 5 Kt of 32 exactly (no padding).
//   Slot s2 = (Nt*5+Kt)*64+lane, elem j <-> B[k=Kt*32+(lane>>4)*8+j][oc=Nt*16+(lane&15)].
//   hi at ws16[26624..31744), lo at ws16[31744..36864).  Total 73,728 B in d_ws.
__global__ __launch_bounds__(256) void prep_kernel(const float* __restrict__ w1,
                                                   const float* __restrict__ w2,
                                                   unsigned short* __restrict__ ws16) {
    int s = blockIdx.x * 256 + threadIdx.x;
    if (s < 1664) {
        int lane = s & 63;
        int ktnt = s >> 6;           // 0..25
        int Kt = ktnt % 13;
        int Nt = ktnt / 13;
        int oc = Nt * 16 + (lane & 15);
        int quad = lane >> 4;
        for (int j = 0; j < 8; ++j) {
            int kp = Kt * 32 + quad * 8 + j;
            int kw = kp & 15, ickh = kp >> 4;
            float w = 0.f;
            if (kw < 11 && ickh < 25) w = w1[oc * 275 + ickh * 11 + kw];
            unsigned short h = f2bf_rne(w);
            ws16[s * 8 + j] = h;
            ws16[13312 + s * 8 + j] = f2bf_rne(w - bf2f(h));
        }
    } else if (s < 2304) {
        int s2 = s - 1664;
        int lane = s2 & 63;
        int ktnt = s2 >> 6;          // 0..9
        int Kt = ktnt % 5;
        int Nt = ktnt / 5;
        int oc = Nt * 16 + (lane & 15);
        int quad = lane >> 4;
        for (int j = 0; j < 8; ++j) {
            int k = Kt * 32 + quad * 8 + j;      // 0..159, always valid
            int ic = k / 5, kw = k - ic * 5;
            float w = w2[oc * 160 + ic * 5 + kw];
            unsigned short h = f2bf_rne(w);
            ws16[26624 + s2 * 8 + j] = h;
            ws16[31744 + s2 * 8 + j] = f2bf_rne(w - bf2f(h));
        }
    }
}

// ======== main kernel ========
// LDS (floats): per-item stride IT=4648 (%32==8):
//   [0,2112)    : xh [5][5][25]x2half=1250 (ph 0-1), then aT [2][32][33] (ph 2+)
//   [2112,3776) : ph 0.5-1: conv1 A-panels abf (dwords [2112,3956), 1844/item:
//                 per-item region R2=half*25+ickh (50 regions x 36 dwords) +
//                 44 zero slack at [1800,1844) for padded-K overflow reads);
//                 ph 1-epilogue onward: h1 [2][32][26] (h2 aliases, ph 6+)
//   [3776,4640) : abf tail (ph 0.5-1), then p1 [half*432+ic*13+j] (ph 4+),
//                 p2f[384] aliases ph 9+
// cst @9296 [4][32].  Total 9424 floats = 36.8 KB -> 4 blocks/CU.
// NOTE: abf aliases h1 -> a __syncthreads() separates the MFMA loop (abf reads)
// from the h1 epilogue stores.
#define IT 4648
#define H1O 2112
#define P1O 3776
#define CSTO 9296
#define LDS_TOTAL (9296 + 128)
#define ABF_PER_IT 1844

__global__ __launch_bounds__(256, 4) void gcn_kernel(
    const float* __restrict__ x,
    const float* __restrict__ w1, const float* __restrict__ b1,
    const float* __restrict__ g1, const float* __restrict__ be1,
    const float* __restrict__ mu1, const float* __restrict__ va1,
    const float* __restrict__ w2, const float* __restrict__ b2,
    const float* __restrict__ g2, const float* __restrict__ be2,
    const float* __restrict__ mu2, const float* __restrict__ va2,
    const float* __restrict__ lw, const float* __restrict__ lb,
    const unsigned short* __restrict__ ws16,
    float* __restrict__ out)
{
    __shared__ float lds[LDS_TOTAL];
    float* cst = lds + CSTO;

    const int tid = threadIdx.x;
    const int b0  = blockIdx.x * 2;

    // ---- phase 0: load 2 items as float2, remap into xh; BN consts ----
    {
        const float2* xg2 = (const float2*)(x + (size_t)b0 * 1250);
        for (int i2 = tid; i2 < 1250; i2 += 256) {
            float2 v = xg2[i2];
            int i = 2 * i2;
            int it = (i >= 1250) ? 1 : 0;
            int j = i - it * 1250;
            int c = j / 250; int r = j - c * 250;
            int h = r / 50;  int w50 = r - h * 50;
            int ha = (w50 >= 25) ? 1 : 0;
            lds[it * IT + ((ha * 5 + c) * 5 + h) * 25 + (w50 - ha * 25)] = v.x;
            int w51 = w50 + 1;
            int hb = (w51 >= 25) ? 1 : 0;
            lds[it * IT + ((hb * 5 + c) * 5 + h) * 25 + (w51 - hb * 25)] = v.y;
        }
    }
    if (tid < 64) {
        int oc = tid & 31;
        if (tid < 32) {
            float inv = g1[oc] * rsqrtf(va1[oc] + BN_EPS);
            cst[oc]      = inv;
            cst[32 + oc] = be1[oc] - mu1[oc] * inv;
        } else {
            float inv = g2[oc] * rsqrtf(va2[oc] + BN_EPS);
            cst[64 + oc] = inv;
            cst[96 + oc] = be2[oc] - mu2[oc] * inv;
        }
    }
    __syncthreads();

    // ---- phase 0.5: stage bf16-RNE A panels (2 parity copies + halo) ----
    // Per-item abf lives at dword offset it*IT + H1O (aliases the h1/p1 space,
    // which is only written after phase 1). d2 in [1800,1844) is zero slack.
    {
        unsigned* abf0 = (unsigned*)lds;
        for (int d = tid; d < 2 * ABF_PER_IT; d += 256) {
            int it = (d >= ABF_PER_IT) ? 1 : 0;
            int d2 = d - it * ABF_PER_IT;
            unsigned u = 0;
            if (d2 < 1800) {
                int R2 = d2 / 36, o = d2 - R2 * 36;
                int cp = (o >= 18) ? 1 : 0;
                int half = (R2 >= 25) ? 1 : 0;
                int ickh = R2 - half * 25;
                int e = 2 * o - (cp ? 37 : 0);
                const float* src = &lds[it * IT + (half * 25 + ickh) * 25];
                int p0 = e + 20; if (p0 >= 25) p0 -= 25; if (p0 >= 25) p0 -= 25;
                int p1 = e + 21; if (p1 >= 25) p1 -= 25; if (p1 >= 25) p1 -= 25;
                u = (unsigned)f2bf_rne(src[p0]) | ((unsigned)f2bf_rne(src[p1]) << 16);
            }
            abf0[it * IT + H1O + d2] = u;
        }
    }
    __syncthreads();

    // ---- phase 1: conv1 via MFMA 16x16x32 bf16 (A bf16-RNE, B=hi+lo) ----
    // wave -> (item = w>>1, M-tile pair = (w&1)*2); M rows: m=half*25+pos (<50).
    {
        const int wave = tid >> 6, lane = tid & 63;
        const int it = wave >> 1;
        const int Mtb = (wave & 1) * 2;
        const int quad = lane >> 4, m16 = lane & 15;
        const int kw0 = (quad & 1) * 8;
        const int ickh0 = quad >> 1;
        const unsigned* abf = (const unsigned*)lds;   // dword-indexed

        int dwb[2];
#pragma unroll
        for (int mt = 0; mt < 2; ++mt) {
            int mg = (Mtb + mt) * 16 + m16;
            int half = (mg >= 25) ? 1 : 0;
            int pos = mg - half * 25; pos = (pos > 24) ? 24 : pos;  // pad rows clamp
            int e0 = pos + kw0;
            int c = e0 & 1;
            int R2b = half * 25 + ickh0;
            dwb[mt] = it * IT + H1O + R2b * 36 + c * 18 + ((e0 + c) >> 1);
        }

        v4f zz = {0.f, 0.f, 0.f, 0.f};
        v4f acc[2][2];
        acc[0][0] = zz; acc[0][1] = zz; acc[1][0] = zz; acc[1][1] = zz;

        for (int Kt = 0; Kt < 13; ++Kt) {
            union { unsigned u[4]; short8 v; } af[2];
#pragma unroll
            for (int mt = 0; mt < 2; ++mt) {
                int base = dwb[mt] + Kt * 72;   // R2 advances by 2 per Kt
                af[mt].u[0] = abf[base + 0];
                af[mt].u[1] = abf[base + 1];
                af[mt].u[2] = abf[base + 2];
                af[mt].u[3] = abf[base + 3];
            }
#pragma unroll
            for (int nt = 0; nt < 2; ++nt) {
                const short8* ph = (const short8*)(ws16 + ((nt * 13 + Kt) * 64 + lane) * 8);
                const short8* pl = (const short8*)(ws16 + 13312 + ((nt * 13 + Kt) * 64 + lane) * 8);
                short8 bh = *ph;
                short8 bl = *pl;
#pragma unroll
                for (int mt = 0; mt < 2; ++mt) {
                    acc[mt][nt] = __builtin_amdgcn_mfma_f32_16x16x32_bf16(af[mt].v, bh, acc[mt][nt], 0, 0, 0);
                    acc[mt][nt] = __builtin_amdgcn_mfma_f32_16x16x32_bf16(af[mt].v, bl, acc[mt][nt], 0, 0, 0);
                }
            }
        }

        // abf (aliased with h1) is dead only once ALL waves finished their MFMAs
        __syncthreads();

        // epilogue: D col=lane&15 (oc within tile), row=quad*4+r; add bias, store h1
        float bias0 = b1[m16], bias1 = b1[16 + m16];
        float* hdst = &lds[it * IT + H1O];
#pragma unroll
        for (int mt = 0; mt < 2; ++mt) {
#pragma unroll
            for (int r = 0; r < 4; ++r) {
                int mg = (Mtb + mt) * 16 + quad * 4 + r;
                if (mg < 50) {
                    int half = (mg >= 25) ? 1 : 0;
                    int pos = mg - half * 25;
                    hdst[(half * 32 + m16) * 26 + pos]      = acc[mt][0][r] + bias0;
                    hdst[(half * 32 + 16 + m16) * 26 + pos] = acc[mt][1][r] + bias1;
                }
            }
        }
    }
    __syncthreads();

    // ---- phase 2: scores a[n][m]=<h1[n],h1[m]>, leaky -> aT[m][n] (over xh) ----
    {
        int n = tid & 31, grp = tid >> 5;
        int it = grp >> 2, mq = grp & 3;
        const float* H = &lds[it * IT + H1O];
        float* A = &lds[it * IT];
#pragma unroll
        for (int half = 0; half < 2; ++half) {
            float pn[25];
            const float* bp = &H[(half * 32 + n) * 26];
            const float2* bp2 = (const float2*)bp;
#pragma unroll
            for (int f2 = 0; f2 < 12; ++f2) {
                float2 v = bp2[f2];
                pn[2 * f2] = v.x; pn[2 * f2 + 1] = v.y;
            }
            pn[24] = bp[24];
#pragma unroll
            for (int i = 0; i < 8; ++i) {
                int m = mq * 8 + i;
                const float* pm = &H[(half * 32 + m) * 26];
                const float2* pm2 = (const float2*)pm;
                float s = 0.f;
#pragma unroll
                for (int f2 = 0; f2 < 12; ++f2) {
                    float2 v = pm2[f2];
                    s += pn[2 * f2] * v.x + pn[2 * f2 + 1] * v.y;
                }
                s += pn[24] * pm[24];
                s = (s > 0.f) ? s : ALPHA * s;
                A[(half * 32 + m) * 33 + n] = s;
            }
        }
    }
    __syncthreads();

    // ---- phase 3: softmax over n; 128 rows x 2 lanes ----
    {
        int row = tid >> 1, q = tid & 1;
        int it = row >> 6, rm = row & 63;
        float* rp = &lds[it * IT + rm * 33];
        float ev[16];
        float mx = -INFINITY;
#pragma unroll
        for (int k = 0; k < 16; ++k) { ev[k] = rp[q + 2 * k]; mx = fmaxf(mx, ev[k]); }
        mx = fmaxf(mx, __shfl_xor(mx, 1));
        float s = 0.f;
#pragma unroll
        for (int k = 0; k < 16; ++k) { ev[k] = __expf(ev[k] - mx); s += ev[k]; }
        s += __shfl_xor(s, 1);
        float inv = 1.f / s;
#pragma unroll
        for (int k = 0; k < 16; ++k) rp[q + 2 * k] = ev[k] * inv;
    }
    __syncthreads();

    // ---- phase 4+5: (att @ h1) -> bn1 -> maxpool2 -> relu -> p1 ----
    for (int e = tid; e < 1536; e += 256) {
        int it = (e >= 768) ? 1 : 0;
        int r = e - it * 768;
        int half = (r >= 384) ? 1 : 0;
        int r2 = r - half * 384;
        int n = r2 / 12, j = r2 - n * 12;
        const float* A = &lds[it * IT + half * 1056 + n];
        const float2* hv2 = (const float2*)&lds[it * IT + H1O + half * 832 + 2 * j];
        float s0 = 0.f, s1 = 0.f;
#pragma unroll
        for (int m = 0; m < 32; ++m) {
            float a = A[m * 33];
            float2 v = hv2[m * 13];
            s0 += a * v.x;
            s1 += a * v.y;
        }
        float inv = cst[n], sh = cst[32 + n];
        float v0 = s0 * inv + sh, v1 = s1 * inv + sh;
        lds[it * IT + P1O + half * 432 + n * 13 + j] = fmaxf(fmaxf(v0, v1), 0.f);
    }
    __syncthreads();

    // ---- phase 6: conv2 via MFMA 16x16x32 bf16 ----
    // wave -> (it = w>>1, half = w&1): GEMM M=12 (ow, pad16), N=32 (oc, 2 tiles),
    // K=160 (k=ic*5+kw, 5 Kt). A built in-register from p1 (hi/lo split);
    // B = w2 fragments (hi/lo) streamed from ws16. 3-term: AhBh + AhBl + AlBh.
    {
        const int wave = tid >> 6, lane = tid & 63;
        const int it = wave >> 1, half = wave & 1;
        const int m16 = lane & 15, quad = lane >> 4;
        const float* pbase = &lds[it * IT + P1O + half * 432];
        float* hout = &lds[it * IT + H1O + half * 432];

        v4f zz = {0.f, 0.f, 0.f, 0.f};
        v4f acc[2]; acc[0] = zz; acc[1] = zz;

#pragma unroll
        for (int Kt = 0; Kt < 5; ++Kt) {
            // ---- build A hi/lo fragments from p1 (8 consecutive k per lane) ----
            union { unsigned u[4]; short8 v; } ah, al;
            int k0 = Kt * 32 + quad * 8;
            int ic = k0 / 5;
            int kw = k0 - ic * 5;
#pragma unroll
            for (int d = 0; d < 4; ++d) {
                unsigned uh = 0, ul = 0;
#pragma unroll
                for (int t = 0; t < 2; ++t) {
                    int pos = m16 + kw - 2;          // m16<=15, kw<=4 -> [-2,17]
                    if (pos < 0) pos += 12;          // [0,17]
                    if (pos >= 12) pos -= 12;        // [0,11]
                    float v = pbase[ic * 13 + pos];  // rows >=12 read junk, discarded
                    unsigned short h = f2bf_rne(v);
                    unsigned short l = f2bf_rne(v - bf2f(h));
                    uh |= ((unsigned)h) << (16 * t);
                    ul |= ((unsigned)l) << (16 * t);
                    ++kw; if (kw == 5) { kw = 0; ++ic; }
                }
                ah.u[d] = uh; al.u[d] = ul;
            }
            // ---- B fragments (hi/lo) and MFMAs ----
#pragma unroll
            for (int nt = 0; nt < 2; ++nt) {
                const short8* ph = (const short8*)(ws16 + 26624 + ((nt * 5 + Kt) * 64 + lane) * 8);
                const short8* pl = (const short8*)(ws16 + 31744 + ((nt * 5 + Kt) * 64 + lane) * 8);
                short8 bh = *ph;
                short8 bl = *pl;
                acc[nt] = __builtin_amdgcn_mfma_f32_16x16x32_bf16(ah.v, bh, acc[nt], 0, 0, 0);
                acc[nt] = __builtin_amdgcn_mfma_f32_16x16x32_bf16(ah.v, bl, acc[nt], 0, 0, 0);
                acc[nt] = __builtin_amdgcn_mfma_f32_16x16x32_bf16(al.v, bh, acc[nt], 0, 0, 0);
            }
        }

        // epilogue: D col=lane&15 (oc in tile), row=quad*4+r = ow; rows>=12 dropped
        if (quad < 3) {
            float bias0 = b2[m16], bias1 = b2[16 + m16];
#pragma unroll
            for (int r = 0; r < 4; ++r) {
                int ow = quad * 4 + r;
                hout[m16 * 13 + ow]        = acc[0][r] + bias0;
                hout[(16 + m16) * 13 + ow] = acc[1][r] + bias1;
            }
        }
    }
    __syncthreads();

    // ---- phase 7: layer-2 scores ----
    {
        int n = tid & 31, grp = tid >> 5;
        int it = grp >> 2, mq = grp & 3;
        const float* H = &lds[it * IT + H1O];
        float* A = &lds[it * IT];
#pragma unroll
        for (int half = 0; half < 2; ++half) {
            float pn[12];
            const float* bp = &H[half * 432 + n * 13];
#pragma unroll
            for (int f = 0; f < 12; ++f) pn[f] = bp[f];
#pragma unroll
            for (int i = 0; i < 8; ++i) {
                int m = mq * 8 + i;
                const float* pm = &H[(1 - half) * 432 + m * 13];
                float s = 0.f;
#pragma unroll
                for (int f = 0; f < 12; ++f) s += pn[f] * pm[f];
                s = (s > 0.f) ? s : ALPHA * s;
                A[(half * 32 + m) * 33 + n] = s;
            }
        }
    }
    __syncthreads();

    // ---- phase 8: softmax ----
    {
        int row = tid >> 1, q = tid & 1;
        int it = row >> 6, rm = row & 63;
        float* rp = &lds[it * IT + rm * 33];
        float ev[16];
        float mx = -INFINITY;
#pragma unroll
        for (int k = 0; k < 16; ++k) { ev[k] = rp[q + 2 * k]; mx = fmaxf(mx, ev[k]); }
        mx = fmaxf(mx, __shfl_xor(mx, 1));
        float s = 0.f;
#pragma unroll
        for (int k = 0; k < 16; ++k) { ev[k] = __expf(ev[k] - mx); s += ev[k]; }
        s += __shfl_xor(s, 1);
        float inv = 1.f / s;
#pragma unroll
        for (int k = 0; k < 16; ++k) rp[q + 2 * k] = ev[k] * inv;
    }
    __syncthreads();

    // ---- phase 9+10: (att2 @ h2) -> bn2 -> pool -> relu -> p2f (over p1) ----
    for (int e = tid; e < 768; e += 256) {
        int it = (e >= 384) ? 1 : 0;
        int r = e - it * 384;
        int n = r / 12; int rem = r - n * 12;
        int half = (rem >= 6) ? 1 : 0;
        int j = rem - half * 6;
        const float* A  = &lds[it * IT + half * 1056 + n];
        const float* hv = &lds[it * IT + H1O + half * 432 + 2 * j];
        float s0 = 0.f, s1 = 0.f;
#pragma unroll
        for (int m = 0; m < 32; ++m) {
            float a = A[m * 33];
            s0 += a * hv[m * 13];
            s1 += a * hv[m * 13 + 1];
        }
        float inv = cst[64 + n], sh = cst[96 + n];
        lds[it * IT + P1O + r] = fmaxf(fmaxf(s0 * inv + sh, s1 * inv + sh), 0.f);
    }
    __syncthreads();

    // ---- phase 11: linear 384 -> 13, both items; float4 dot ----
    if (tid < 208) {
        int s8 = tid & 7;
        int rest = tid >> 3;
        int it = (rest >= 13) ? 1 : 0;
        int o = rest - it * 13;
        const float4* wv4 = (const float4*)(lw + o * 384 + s8 * 48);
        const float4* fv4 = (const float4*)&lds[it * IT + P1O + s8 * 48];
        float s = 0.f;
#pragma unroll
        for (int i = 0; i < 12; ++i) {
            float4 w4 = wv4[i];
            float4 f4 = fv4[i];
            s += f4.x * w4.x + f4.y * w4.y + f4.z * w4.z + f4.w * w4.w;
        }
        s += __shfl_down(s, 4, 8);
        s += __shfl_down(s, 2, 8);
        s += __shfl_down(s, 1, 8);
        if (s8 == 0) out[(size_t)(b0 + it) * 13 + o] = s + lb[o];
    }
}

extern "C" void kernel_launch(void* const* d_in, const int* in_sizes, int n_in,
                              void* d_out, int out_size, void* d_ws, size_t ws_size,
                              hipStream_t stream) {
    const float* x   = (const float*)d_in[0];
    const float* w1  = (const float*)d_in[1];
    const float* b1  = (const float*)d_in[2];
    const float* g1  = (const float*)d_in[3];
    const float* be1 = (const float*)d_in[4];
    const float* mu1 = (const float*)d_in[5];
    const float* va1 = (const float*)d_in[6];
    const float* w2  = (const float*)d_in[7];
    const float* b2  = (const float*)d_in[8];
    const float* g2  = (const float*)d_in[9];
    const float* be2 = (const float*)d_in[10];
    const float* mu2 = (const float*)d_in[11];
    const float* va2 = (const float*)d_in[12];
    const float* lw  = (const float*)d_in[13];
    const float* lb  = (const float*)d_in[14];
    float* out = (float*)d_out;
    unsigned short* ws16 = (unsigned short*)d_ws;

    // pack conv1 + conv2 weights into MFMA B-fragments (hi/lo bf16), 73.7 KB in d_ws
    prep_kernel<<<9, 256, 0, stream>>>(w1, w2, ws16);

    int B = in_sizes[0] / 1250;  // 16384
    gcn_kernel<<<B / 2, 256, 0, stream>>>(x, w1, b1, g1, be1, mu1, va1,
                                          w2, b2, g2, be2, mu2, va2, lw, lb,
                                          ws16, out);
}

// Round 3
// 421.003 us; speedup vs baseline: 1.1220x; 1.0927x over previous
//
#include <hip/hip_runtime.h>
#include <math.h>

#define ALPHA 0.2f
#define BN_EPS 1e-5f

typedef __attribute__((ext_vector_type(8))) short short8;
typedef __attribute__((ext_vector_type(4))) float v4f;

// ---- bf16 bit helpers (RNE) ----
__device__ __forceinline__ unsigned short f2bf_rne(float f) {
    union { float f; unsigned u; } x; x.f = f;
    unsigned r = x.u + 0x7FFFu + ((x.u >> 16) & 1u);
    return (unsigned short)(r >> 16);
}
__device__ __forceinline__ float bf2f(unsigned short h) {
    union { float f; unsigned u; } x; x.u = ((unsigned)h) << 16;
    return x.f;
}

// ======== prep kernel: pack conv1 + conv2 weights as MFMA B-fragments ========
// conv1: K-order k' = ickh*16 + kw (kw 0..15, pad>=11 zero; ickh 0..25, pad 25 zero).
//   Kt = k'/32 in [0,13). Slot s = (Nt*13+Kt)*64+lane holds 8 ushorts:
//   elem j <-> B[k'=Kt*32+(lane>>4)*8+j][oc=Nt*16+(lane&15)].
//   hi at ws16[0..13312), lo at ws16[13312..26624).
// conv2: K-order k = ic*5 + kw, K=160 = 5 Kt of 32 exactly (no padding).
//   Slot s2 = (Nt*5+Kt)*64+lane, elem j <-> B[k=Kt*32+(lane>>4)*8+j][oc=Nt*16+(lane&15)].
//   hi at ws16[26624..31744), lo at ws16[31744..36864).  Total 73,728 B in d_ws.
__global__ __launch_bounds__(256) void prep_kernel(const float* __restrict__ w1,
                                                   const float* __restrict__ w2,
                                                   unsigned short* __restrict__ ws16) {
    int s = blockIdx.x * 256 + threadIdx.x;
    if (s < 1664) {
        int lane = s & 63;
        int ktnt = s >> 6;           // 0..25
        int Kt = ktnt % 13;
        int Nt = ktnt / 13;
        int oc = Nt * 16 + (lane & 15);
        int quad = lane >> 4;
        for (int j = 0; j < 8; ++j) {
            int kp = Kt * 32 + quad * 8 + j;
            int kw = kp & 15, ickh = kp >> 4;
            float w = 0.f;
            if (kw < 11 && ickh < 25) w = w1[oc * 275 + ickh * 11 + kw];
            unsigned short h = f2bf_rne(w);
            ws16[s * 8 + j] = h;
            ws16[13312 + s * 8 + j] = f2bf_rne(w - bf2f(h));
        }
    } else if (s < 2304) {
        int s2 = s - 1664;
        int lane = s2 & 63;
        int ktnt = s2 >> 6;          // 0..9
        int Kt = ktnt % 5;
        int Nt = ktnt / 5;
        int oc = Nt * 16 + (lane & 15);
        int quad = lane >> 4;
        for (int j = 0; j < 8; ++j) {
            int k = Kt * 32 + quad * 8 + j;      // 0..159, always valid
            int ic = k / 5, kw = k - ic * 5;
            float w = w2[oc * 160 + ic * 5 + kw];
            unsigned short h = f2bf_rne(w);
            ws16[26624 + s2 * 8 + j] = h;
            ws16[31744 + s2 * 8 + j] = f2bf_rne(w - bf2f(h));
        }
    }
}

// ======== main kernel ========
// LDS (floats): per-item stride IT=4648 (%32==8):
//   [0,2112)    : xh (ph 0-0.5); hbf bf16 h1 [hi:[64r][32c] lo:+2048us] (ph1 epi-
//                 ph2 reads); aT [2][32][33] f32 (ph2 epi+); h2bf (ph6 epi-ph7
//                 reads); aT2 (ph7 epi+).  All dead/live windows barrier-separated.
//   [2112,3776) : ph 0.5-1: conv1 A-panels abf (1844 dw/item, 44 zero slack);
//                 ph 1-epilogue onward: h1 f32 [2][32][26] (h2 f32 aliases, ph 6+)
//   [3776,4640) : abf tail, then p1 [half*432+ic*13+j] (ph 4+), p2f[384] ph 9+
// cst @9296 [4][32].  Total 9424 floats = 36.8 KB -> 4 blocks/CU.
#define IT 4648
#define H1O 2112
#define P1O 3776
#define CSTO 9296
#define LDS_TOTAL (9296 + 128)
#define ABF_PER_IT 1844

__global__ __launch_bounds__(256, 4) void gcn_kernel(
    const float* __restrict__ x,
    const float* __restrict__ w1, const float* __restrict__ b1,
    const float* __restrict__ g1, const float* __restrict__ be1,
    const float* __restrict__ mu1, const float* __restrict__ va1,
    const float* __restrict__ w2, const float* __restrict__ b2,
    const float* __restrict__ g2, const float* __restrict__ be2,
    const float* __restrict__ mu2, const float* __restrict__ va2,
    const float* __restrict__ lw, const float* __restrict__ lb,
    const unsigned short* __restrict__ ws16,
    float* __restrict__ out)
{
    __shared__ float lds[LDS_TOTAL];
    float* cst = lds + CSTO;

    const int tid = threadIdx.x;
    const int b0  = blockIdx.x * 2;

    // ---- phase 0: load 2 items as float2, remap into xh; BN consts ----
    {
        const float2* xg2 = (const float2*)(x + (size_t)b0 * 1250);
        for (int i2 = tid; i2 < 1250; i2 += 256) {
            float2 v = xg2[i2];
            int i = 2 * i2;
            int it = (i >= 1250) ? 1 : 0;
            int j = i - it * 1250;
            int c = j / 250; int r = j - c * 250;
            int h = r / 50;  int w50 = r - h * 50;
            int ha = (w50 >= 25) ? 1 : 0;
            lds[it * IT + ((ha * 5 + c) * 5 + h) * 25 + (w50 - ha * 25)] = v.x;
            int w51 = w50 + 1;
            int hb = (w51 >= 25) ? 1 : 0;
            lds[it * IT + ((hb * 5 + c) * 5 + h) * 25 + (w51 - hb * 25)] = v.y;
        }
    }
    if (tid < 64) {
        int oc = tid & 31;
        if (tid < 32) {
            float inv = g1[oc] * rsqrtf(va1[oc] + BN_EPS);
            cst[oc]      = inv;
            cst[32 + oc] = be1[oc] - mu1[oc] * inv;
        } else {
            float inv = g2[oc] * rsqrtf(va2[oc] + BN_EPS);
            cst[64 + oc] = inv;
            cst[96 + oc] = be2[oc] - mu2[oc] * inv;
        }
    }
    __syncthreads();

    // ---- phase 0.5: stage bf16-RNE A panels (2 parity copies + halo) ----
    {
        unsigned* abf0 = (unsigned*)lds;
        for (int d = tid; d < 2 * ABF_PER_IT; d += 256) {
            int it = (d >= ABF_PER_IT) ? 1 : 0;
            int d2 = d - it * ABF_PER_IT;
            unsigned u = 0;
            if (d2 < 1800) {
                int R2 = d2 / 36, o = d2 - R2 * 36;
                int cp = (o >= 18) ? 1 : 0;
                int half = (R2 >= 25) ? 1 : 0;
                int ickh = R2 - half * 25;
                int e = 2 * o - (cp ? 37 : 0);
                const float* src = &lds[it * IT + (half * 25 + ickh) * 25];
                int p0 = e + 20; if (p0 >= 25) p0 -= 25; if (p0 >= 25) p0 -= 25;
                int p1 = e + 21; if (p1 >= 25) p1 -= 25; if (p1 >= 25) p1 -= 25;
                u = (unsigned)f2bf_rne(src[p0]) | ((unsigned)f2bf_rne(src[p1]) << 16);
            }
            abf0[it * IT + H1O + d2] = u;
        }
    }
    __syncthreads();

    // ---- phase 1: conv1 via MFMA 16x16x32 bf16 (A bf16-RNE, B=hi+lo) ----
    {
        const int wave = tid >> 6, lane = tid & 63;
        const int it = wave >> 1;
        const int Mtb = (wave & 1) * 2;
        const int quad = lane >> 4, m16 = lane & 15;
        const int kw0 = (quad & 1) * 8;
        const int ickh0 = quad >> 1;
        const unsigned* abf = (const unsigned*)lds;   // dword-indexed

        int dwb[2];
#pragma unroll
        for (int mt = 0; mt < 2; ++mt) {
            int mg = (Mtb + mt) * 16 + m16;
            int half = (mg >= 25) ? 1 : 0;
            int pos = mg - half * 25; pos = (pos > 24) ? 24 : pos;  // pad rows clamp
            int e0 = pos + kw0;
            int c = e0 & 1;
            int R2b = half * 25 + ickh0;
            dwb[mt] = it * IT + H1O + R2b * 36 + c * 18 + ((e0 + c) >> 1);
        }

        v4f zz = {0.f, 0.f, 0.f, 0.f};
        v4f acc[2][2];
        acc[0][0] = zz; acc[0][1] = zz; acc[1][0] = zz; acc[1][1] = zz;

        for (int Kt = 0; Kt < 13; ++Kt) {
            union { unsigned u[4]; short8 v; } af[2];
#pragma unroll
            for (int mt = 0; mt < 2; ++mt) {
                int base = dwb[mt] + Kt * 72;   // R2 advances by 2 per Kt
                af[mt].u[0] = abf[base + 0];
                af[mt].u[1] = abf[base + 1];
                af[mt].u[2] = abf[base + 2];
                af[mt].u[3] = abf[base + 3];
            }
#pragma unroll
            for (int nt = 0; nt < 2; ++nt) {
                const short8* ph = (const short8*)(ws16 + ((nt * 13 + Kt) * 64 + lane) * 8);
                const short8* pl = (const short8*)(ws16 + 13312 + ((nt * 13 + Kt) * 64 + lane) * 8);
                short8 bh = *ph;
                short8 bl = *pl;
#pragma unroll
                for (int mt = 0; mt < 2; ++mt) {
                    acc[mt][nt] = __builtin_amdgcn_mfma_f32_16x16x32_bf16(af[mt].v, bh, acc[mt][nt], 0, 0, 0);
                    acc[mt][nt] = __builtin_amdgcn_mfma_f32_16x16x32_bf16(af[mt].v, bl, acc[mt][nt], 0, 0, 0);
                }
            }
        }

        // abf (aliased with h1) and xh (aliased with hbf) dead after all MFMAs
        __syncthreads();

        // zero hbf pad cols 25..31 (hi and lo), both items: 2*64*7 = 896 els
        for (int z = tid; z < 896; z += 256) {
            int itz = (z >= 448) ? 1 : 0;
            int r2 = z - itz * 448;
            int row = r2 / 7, c = 25 + (r2 - row * 7);
            unsigned short* hbz = (unsigned short*)(lds + itz * IT);
            hbz[row * 32 + c] = 0;
            hbz[2048 + row * 32 + c] = 0;
        }

        // epilogue: D col=lane&15 (oc within tile), row=quad*4+r; add bias,
        // store h1 f32 AND bf16 hi/lo copy (hbf, layout [half*32+oc][pos pad32])
        float bias0 = b1[m16], bias1 = b1[16 + m16];
        float* hdst = &lds[it * IT + H1O];
        unsigned short* hbu = (unsigned short*)(lds + it * IT);
#pragma unroll
        for (int mt = 0; mt < 2; ++mt) {
#pragma unroll
            for (int r = 0; r < 4; ++r) {
                int mg = (Mtb + mt) * 16 + quad * 4 + r;
                if (mg < 50) {
                    int half = (mg >= 25) ? 1 : 0;
                    int pos = mg - half * 25;
                    float v0 = acc[mt][0][r] + bias0;
                    float v1 = acc[mt][1][r] + bias1;
                    hdst[(half * 32 + m16) * 26 + pos]      = v0;
                    hdst[(half * 32 + 16 + m16) * 26 + pos] = v1;
                    int r0 = (half * 32 + m16) * 32 + pos;
                    int r1 = (half * 32 + 16 + m16) * 32 + pos;
                    unsigned short h0 = f2bf_rne(v0);
                    unsigned short h1v = f2bf_rne(v1);
                    hbu[r0] = h0; hbu[2048 + r0] = f2bf_rne(v0 - bf2f(h0));
                    hbu[r1] = h1v; hbu[2048 + r1] = f2bf_rne(v1 - bf2f(h1v));
                }
            }
        }
    }
    __syncthreads();

    // ---- phase 2: scores via MFMA Gram trick: S[m][n] = <H[m],H[n]> ----
    // wave -> (it, half). A-frag == B-frag (row-major b128 reads of hbf).
    // 3-term hi/lo: HhHh^T + HhHl^T + HlHh^T. Then leaky -> aT[m][n].
    {
        const int wave = tid >> 6, lane = tid & 63;
        const int it = wave >> 1, half = wave & 1;
        const int m16 = lane & 15, q = lane >> 4;
        const unsigned short* hb = (const unsigned short*)(lds + it * IT);
        short8 fh[2], fl[2];
#pragma unroll
        for (int t = 0; t < 2; ++t) {
            int row = half * 32 + t * 16 + m16;
            fh[t] = *(const short8*)(hb + row * 32 + q * 8);
            fl[t] = *(const short8*)(hb + 2048 + row * 32 + q * 8);
        }
        v4f zz = {0.f, 0.f, 0.f, 0.f};
        v4f acc[2][2];
        acc[0][0] = zz; acc[0][1] = zz; acc[1][0] = zz; acc[1][1] = zz;
#pragma unroll
        for (int mt = 0; mt < 2; ++mt)
#pragma unroll
            for (int nt = 0; nt < 2; ++nt) {
                acc[mt][nt] = __builtin_amdgcn_mfma_f32_16x16x32_bf16(fh[mt], fh[nt], acc[mt][nt], 0, 0, 0);
                acc[mt][nt] = __builtin_amdgcn_mfma_f32_16x16x32_bf16(fh[mt], fl[nt], acc[mt][nt], 0, 0, 0);
                acc[mt][nt] = __builtin_amdgcn_mfma_f32_16x16x32_bf16(fl[mt], fh[nt], acc[mt][nt], 0, 0, 0);
            }
        __syncthreads();   // hbf dead; safe to overwrite with aT
        float* A = &lds[it * IT];
#pragma unroll
        for (int mt = 0; mt < 2; ++mt)
#pragma unroll
            for (int nt = 0; nt < 2; ++nt)
#pragma unroll
                for (int r = 0; r < 4; ++r) {
                    int m = mt * 16 + q * 4 + r;
                    int n = nt * 16 + m16;
                    float s = acc[mt][nt][r];
                    s = (s > 0.f) ? s : ALPHA * s;
                    A[(half * 32 + m) * 33 + n] = s;
                }
    }
    __syncthreads();

    // ---- phase 3: softmax over n; 128 rows x 2 lanes ----
    {
        int row = tid >> 1, q = tid & 1;
        int it = row >> 6, rm = row & 63;
        float* rp = &lds[it * IT + rm * 33];
        float ev[16];
        float mx = -INFINITY;
#pragma unroll
        for (int k = 0; k < 16; ++k) { ev[k] = rp[q + 2 * k]; mx = fmaxf(mx, ev[k]); }
        mx = fmaxf(mx, __shfl_xor(mx, 1));
        float s = 0.f;
#pragma unroll
        for (int k = 0; k < 16; ++k) { ev[k] = __expf(ev[k] - mx); s += ev[k]; }
        s += __shfl_xor(s, 1);
        float inv = 1.f / s;
#pragma unroll
        for (int k = 0; k < 16; ++k) rp[q + 2 * k] = ev[k] * inv;
    }
    __syncthreads();

    // ---- phase 4+5: (att @ h1) -> bn1 -> maxpool2 -> relu -> p1 ----
    for (int e = tid; e < 1536; e += 256) {
        int it = (e >= 768) ? 1 : 0;
        int r = e - it * 768;
        int half = (r >= 384) ? 1 : 0;
        int r2 = r - half * 384;
        int n = r2 / 12, j = r2 - n * 12;
        const float* A = &lds[it * IT + half * 1056 + n];
        const float2* hv2 = (const float2*)&lds[it * IT + H1O + half * 832 + 2 * j];
        float s0 = 0.f, s1 = 0.f;
#pragma unroll
        for (int m = 0; m < 32; ++m) {
            float a = A[m * 33];
            float2 v = hv2[m * 13];
            s0 += a * v.x;
            s1 += a * v.y;
        }
        float inv = cst[n], sh = cst[32 + n];
        float v0 = s0 * inv + sh, v1 = s1 * inv + sh;
        lds[it * IT + P1O + half * 432 + n * 13 + j] = fmaxf(fmaxf(v0, v1), 0.f);
    }
    __syncthreads();

    // ---- phase 6: conv2 via MFMA 16x16x32 bf16; also emit h2bf (bf16 hi/lo) ----
    {
        const int wave = tid >> 6, lane = tid & 63;
        const int it = wave >> 1, half = wave & 1;
        const int m16 = lane & 15, quad = lane >> 4;
        const float* pbase = &lds[it * IT + P1O + half * 432];
        float* hout = &lds[it * IT + H1O + half * 432];

        // zero h2bf pad cols 12..31 (dw cols 6..15), hi+lo, both items
        for (int z = tid; z < 2560; z += 256) {
            int itz = (z >= 1280) ? 1 : 0;
            int r2 = z - itz * 1280;
            int hl = (r2 >= 640) ? 1 : 0;
            int r3 = r2 - hl * 640;
            int row = r3 / 10, c6 = 6 + (r3 - row * 10);
            ((unsigned*)(lds + itz * IT))[hl * 1024 + row * 16 + c6] = 0;
        }

        v4f zz = {0.f, 0.f, 0.f, 0.f};
        v4f acc[2]; acc[0] = zz; acc[1] = zz;

#pragma unroll
        for (int Kt = 0; Kt < 5; ++Kt) {
            // ---- build A hi/lo fragments from p1 (8 consecutive k per lane) ----
            union { unsigned u[4]; short8 v; } ah, al;
            int k0 = Kt * 32 + quad * 8;
            int ic = k0 / 5;
            int kw = k0 - ic * 5;
#pragma unroll
            for (int d = 0; d < 4; ++d) {
                unsigned uh = 0, ul = 0;
#pragma unroll
                for (int t = 0; t < 2; ++t) {
                    int pos = m16 + kw - 2;          // m16<=15, kw<=4 -> [-2,17]
                    if (pos < 0) pos += 12;          // [0,17]
                    if (pos >= 12) pos -= 12;        // [0,11]
                    float v = pbase[ic * 13 + pos];  // rows >=12 read junk, discarded
                    unsigned short h = f2bf_rne(v);
                    unsigned short l = f2bf_rne(v - bf2f(h));
                    uh |= ((unsigned)h) << (16 * t);
                    ul |= ((unsigned)l) << (16 * t);
                    ++kw; if (kw == 5) { kw = 0; ++ic; }
                }
                ah.u[d] = uh; al.u[d] = ul;
            }
            // ---- B fragments (hi/lo) and MFMAs ----
#pragma unroll
            for (int nt = 0; nt < 2; ++nt) {
                const short8* ph = (const short8*)(ws16 + 26624 + ((nt * 5 + Kt) * 64 + lane) * 8);
                const short8* pl = (const short8*)(ws16 + 31744 + ((nt * 5 + Kt) * 64 + lane) * 8);
                short8 bh = *ph;
                short8 bl = *pl;
                acc[nt] = __builtin_amdgcn_mfma_f32_16x16x32_bf16(ah.v, bh, acc[nt], 0, 0, 0);
                acc[nt] = __builtin_amdgcn_mfma_f32_16x16x32_bf16(ah.v, bl, acc[nt], 0, 0, 0);
                acc[nt] = __builtin_amdgcn_mfma_f32_16x16x32_bf16(al.v, bh, acc[nt], 0, 0, 0);
            }
        }

        // epilogue: D col=lane&15 (oc in tile), row=quad*4+r = ow; rows>=12 dropped
        // write h2 f32 AND h2bf (bf16 hi/lo, [half*32+oc][ow pad32], dword-packed)
        if (quad < 3) {
            float bias0 = b2[m16], bias1 = b2[16 + m16];
            unsigned* hb2d = (unsigned*)(lds + it * IT);
#pragma unroll
            for (int nt = 0; nt < 2; ++nt) {
                float bias = nt ? bias1 : bias0;
                int oc = nt * 16 + m16;
                int row = half * 32 + oc;
                float v[4]; unsigned short hh[4], ll[4];
#pragma unroll
                for (int r = 0; r < 4; ++r) {
                    v[r] = acc[nt][r] + bias;
                    hout[oc * 13 + quad * 4 + r] = v[r];
                    hh[r] = f2bf_rne(v[r]);
                    ll[r] = f2bf_rne(v[r] - bf2f(hh[r]));
                }
                hb2d[row * 16 + quad * 2 + 0] = (unsigned)hh[0] | ((unsigned)hh[1] << 16);
                hb2d[row * 16 + quad * 2 + 1] = (unsigned)hh[2] | ((unsigned)hh[3] << 16);
                hb2d[1024 + row * 16 + quad * 2 + 0] = (unsigned)ll[0] | ((unsigned)ll[1] << 16);
                hb2d[1024 + row * 16 + quad * 2 + 1] = (unsigned)ll[2] | ((unsigned)ll[3] << 16);
            }
        }
    }
    __syncthreads();

    // ---- phase 7: layer-2 scores via MFMA: S[m][n] = <H2[1-half][m], H2[half][n]> ----
    {
        const int wave = tid >> 6, lane = tid & 63;
        const int it = wave >> 1, half = wave & 1;
        const int m16 = lane & 15, q = lane >> 4;
        const unsigned short* hb2 = (const unsigned short*)(lds + it * IT);
        short8 ah[2], al[2], bh[2], bl[2];
#pragma unroll
        for (int t = 0; t < 2; ++t) {
            int rowA = (1 - half) * 32 + t * 16 + m16;   // A rows: m from other half
            ah[t] = *(const short8*)(hb2 + rowA * 32 + q * 8);
            al[t] = *(const short8*)(hb2 + 2048 + rowA * 32 + q * 8);
            int rowB = half * 32 + t * 16 + m16;         // B cols: n from this half
            bh[t] = *(const short8*)(hb2 + rowB * 32 + q * 8);
            bl[t] = *(const short8*)(hb2 + 2048 + rowB * 32 + q * 8);
        }
        v4f zz = {0.f, 0.f, 0.f, 0.f};
        v4f acc[2][2];
        acc[0][0] = zz; acc[0][1] = zz; acc[1][0] = zz; acc[1][1] = zz;
#pragma unroll
        for (int mt = 0; mt < 2; ++mt)
#pragma unroll
            for (int nt = 0; nt < 2; ++nt) {
                acc[mt][nt] = __builtin_amdgcn_mfma_f32_16x16x32_bf16(ah[mt], bh[nt], acc[mt][nt], 0, 0, 0);
                acc[mt][nt] = __builtin_amdgcn_mfma_f32_16x16x32_bf16(ah[mt], bl[nt], acc[mt][nt], 0, 0, 0);
                acc[mt][nt] = __builtin_amdgcn_mfma_f32_16x16x32_bf16(al[mt], bh[nt], acc[mt][nt], 0, 0, 0);
            }
        __syncthreads();   // h2bf dead; safe to overwrite with aT2
        float* A = &lds[it * IT];
#pragma unroll
        for (int mt = 0; mt < 2; ++mt)
#pragma unroll
            for (int nt = 0; nt < 2; ++nt)
#pragma unroll
                for (int r = 0; r < 4; ++r) {
                    int m = mt * 16 + q * 4 + r;
                    int n = nt * 16 + m16;
                    float s = acc[mt][nt][r];
                    s = (s > 0.f) ? s : ALPHA * s;
                    A[(half * 32 + m) * 33 + n] = s;
                }
    }
    __syncthreads();

    // ---- phase 8: softmax ----
    {
        int row = tid >> 1, q = tid & 1;
        int it = row >> 6, rm = row & 63;
        float* rp = &lds[it * IT + rm * 33];
        float ev[16];
        float mx = -INFINITY;
#pragma unroll
        for (int k = 0; k < 16; ++k) { ev[k] = rp[q + 2 * k]; mx = fmaxf(mx, ev[k]); }
        mx = fmaxf(mx, __shfl_xor(mx, 1));
        float s = 0.f;
#pragma unroll
        for (int k = 0; k < 16; ++k) { ev[k] = __expf(ev[k] - mx); s += ev[k]; }
        s += __shfl_xor(s, 1);
        float inv = 1.f / s;
#pragma unroll
        for (int k = 0; k < 16; ++k) rp[q + 2 * k] = ev[k] * inv;
    }
    __syncthreads();

    // ---- phase 9+10: (att2 @ h2) -> bn2 -> pool -> relu -> p2f (over p1) ----
    for (int e = tid; e < 768; e += 256) {
        int it = (e >= 384) ? 1 : 0;
        int r = e - it * 384;
        int n = r / 12; int rem = r - n * 12;
        int half = (rem >= 6) ? 1 : 0;
        int j = rem - half * 6;
        const float* A  = &lds[it * IT + half * 1056 + n];
        const float* hv = &lds[it * IT + H1O + half * 432 + 2 * j];
        float s0 = 0.f, s1 = 0.f;
#pragma unroll
        for (int m = 0; m < 32; ++m) {
            float a = A[m * 33];
            s0 += a * hv[m * 13];
            s1 += a * hv[m * 13 + 1];
        }
        float inv = cst[64 + n], sh = cst[96 + n];
        lds[it * IT + P1O + r] = fmaxf(fmaxf(s0 * inv + sh, s1 * inv + sh), 0.f);
    }
    __syncthreads();

    // ---- phase 11: linear 384 -> 13, both items; float4 dot ----
    if (tid < 208) {
        int s8 = tid & 7;
        int rest = tid >> 3;
        int it = (rest >= 13) ? 1 : 0;
        int o = rest - it * 13;
        const float4* wv4 = (const float4*)(lw + o * 384 + s8 * 48);
        const float4* fv4 = (const float4*)&lds[it * IT + P1O + s8 * 48];
        float s = 0.f;
#pragma unroll
        for (int i = 0; i < 12; ++i) {
            float4 w4 = wv4[i];
            float4 f4 = fv4[i];
            s += f4.x * w4.x + f4.y * w4.y + f4.z * w4.z + f4.w * w4.w;
        }
        s += __shfl_down(s, 4, 8);
        s += __shfl_down(s, 2, 8);
        s += __shfl_down(s, 1, 8);
        if (s8 == 0) out[(size_t)(b0 + it) * 13 + o] = s + lb[o];
    }
}

extern "C" void kernel_launch(void* const* d_in, const int* in_sizes, int n_in,
                              void* d_out, int out_size, void* d_ws, size_t ws_size,
                              hipStream_t stream) {
    const float* x   = (const float*)d_in[0];
    const float* w1  = (const float*)d_in[1];
    const float* b1  = (const float*)d_in[2];
    const float* g1  = (const float*)d_in[3];
    const float* be1 = (const float*)d_in[4];
    const float* mu1 = (const float*)d_in[5];
    const float* va1 = (const float*)d_in[6];
    const float* w2  = (const float*)d_in[7];
    const float* b2  = (const float*)d_in[8];
    const float* g2  = (const float*)d_in[9];
    const float* be2 = (const float*)d_in[10];
    const float* mu2 = (const float*)d_in[11];
    const float* va2 = (const float*)d_in[12];
    const float* lw  = (const float*)d_in[13];
    const float* lb  = (const float*)d_in[14];
    float* out = (float*)d_out;
    unsigned short* ws16 = (unsigned short*)d_ws;

    // pack conv1 + conv2 weights into MFMA B-fragments (hi/lo bf16), 73.7 KB in d_ws
    prep_kernel<<<9, 256, 0, stream>>>(w1, w2, ws16);

    int B = in_sizes[0] / 1250;  // 16384
    gcn_kernel<<<B / 2, 256, 0, stream>>>(x, w1, b1, g1, be1, mu1, va1,
                                          w2, b2, g2, be2, mu2, va2, lw, lb,
                                          ws16, out);
}

// Round 4
// 304.663 us; speedup vs baseline: 1.5504x; 1.3819x over previous
//
#include <hip/hip_runtime.h>
#include <math.h>

#define ALPHA 0.2f
#define BN_EPS 1e-5f

typedef __attribute__((ext_vector_type(8))) short short8;
typedef __attribute__((ext_vector_type(4))) float v4f;

// ---- bf16 bit helpers (RNE) ----
__device__ __forceinline__ unsigned short f2bf_rne(float f) {
    union { float f; unsigned u; } x; x.f = f;
    unsigned r = x.u + 0x7FFFu + ((x.u >> 16) & 1u);
    return (unsigned short)(r >> 16);
}
__device__ __forceinline__ float bf2f(unsigned short h) {
    union { float f; unsigned u; } x; x.u = ((unsigned)h) << 16;
    return x.f;
}

// ======== prep kernel: pack conv1 + conv2 weights as MFMA B-fragments ========
// conv1: K-order k' = ickh*16 + kw (kw 0..15, pad>=11 zero; ickh 0..25, pad 25 zero).
//   Kt = k'/32 in [0,13). Slot s = (Nt*13+Kt)*64+lane holds 8 ushorts:
//   elem j <-> B[k'=Kt*32+(lane>>4)*8+j][oc=Nt*16+(lane&15)].
//   hi at ws16[0..13312), lo at ws16[13312..26624).
// conv2 (kw-split, 5 GEMMs of K=32=ic): slot s2 = ((kw*2+nt)*64+lane):
//   elem j <-> B_kw[ic=(lane>>4)*8+j][oc=nt*16+(lane&15)] = w2[oc][ic][kw].
//   hi at ws16[26624..31744), lo at ws16[31744..36864).
__global__ __launch_bounds__(256) void prep_kernel(const float* __restrict__ w1,
                                                   const float* __restrict__ w2,
                                                   unsigned short* __restrict__ ws16) {
    int s = blockIdx.x * 256 + threadIdx.x;
    if (s < 1664) {
        int lane = s & 63;
        int ktnt = s >> 6;           // 0..25
        int Kt = ktnt % 13;
        int Nt = ktnt / 13;
        int oc = Nt * 16 + (lane & 15);
        int quad = lane >> 4;
        for (int j = 0; j < 8; ++j) {
            int kp = Kt * 32 + quad * 8 + j;
            int kw = kp & 15, ickh = kp >> 4;
            float w = 0.f;
            if (kw < 11 && ickh < 25) w = w1[oc * 275 + ickh * 11 + kw];
            unsigned short h = f2bf_rne(w);
            ws16[s * 8 + j] = h;
            ws16[13312 + s * 8 + j] = f2bf_rne(w - bf2f(h));
        }
    } else if (s < 2304) {
        int s2 = s - 1664;
        int lane = s2 & 63;
        int ktnt = s2 >> 6;          // 0..9 = kw*2+nt
        int kw = ktnt >> 1;
        int nt = ktnt & 1;
        int oc = nt * 16 + (lane & 15);
        int quad = lane >> 4;
        for (int j = 0; j < 8; ++j) {
            int ic = quad * 8 + j;
            float w = w2[oc * 160 + ic * 5 + kw];
            unsigned short h = f2bf_rne(w);
            ws16[26624 + s2 * 8 + j] = h;
            ws16[31744 + s2 * 8 + j] = f2bf_rne(w - bf2f(h));
        }
    }
}

// ======== main kernel ========
// Per-item LDS regions (dwords, stride IT=4648):
//  [0,2112)   : xh input (ph0-1); hbf = bf16 h1 k-major pair-packed:
//               hi dw kd*66+ch (kd=f>>1, 16x66), lo +1056  (ph1-epi..ph4+5);
//               pt (conv2 A, [half*416 + kd*13 + pos], hi/lo +208) (ph4+5-epi..ph6);
//               h2bf at dw 1056: hi kd*66+ch (kd 0..7 x 66), lo +528 (ph6-epi..ph9+10)
//  [2112,4224): abf conv1 A-panels (1844/item, ph0.5-1); aT/aT2 f32 [64][33] (ph2+)
//  [4224,4608): p2f f32 [384] (ph9+10-epi..ph11)
// cst @9296 [4][32]. Total 9424 dw = 37696 B -> 4 blocks/CU.
#define IT 4648
#define ATO 2112
#define P2O 4224
#define CSTO 9296
#define LDS_TOTAL (9296 + 128)
#define ABF_PER_IT 1844

__global__ __launch_bounds__(256, 4) void gcn_kernel(
    const float* __restrict__ x,
    const float* __restrict__ w1, const float* __restrict__ b1,
    const float* __restrict__ g1, const float* __restrict__ be1,
    const float* __restrict__ mu1, const float* __restrict__ va1,
    const float* __restrict__ w2, const float* __restrict__ b2,
    const float* __restrict__ g2, const float* __restrict__ be2,
    const float* __restrict__ mu2, const float* __restrict__ va2,
    const float* __restrict__ lw, const float* __restrict__ lb,
    const unsigned short* __restrict__ ws16,
    float* __restrict__ out)
{
    __shared__ float lds[LDS_TOTAL];
    float* cst = lds + CSTO;

    const int tid = threadIdx.x;
    const int b0  = blockIdx.x * 2;

    // ---- phase 0: load 2 items as float2, remap into xh; BN consts ----
    {
        const float2* xg2 = (const float2*)(x + (size_t)b0 * 1250);
        for (int i2 = tid; i2 < 1250; i2 += 256) {
            float2 v = xg2[i2];
            int i = 2 * i2;
            int it = (i >= 1250) ? 1 : 0;
            int j = i - it * 1250;
            int c = j / 250; int r = j - c * 250;
            int h = r / 50;  int w50 = r - h * 50;
            int ha = (w50 >= 25) ? 1 : 0;
            lds[it * IT + ((ha * 5 + c) * 5 + h) * 25 + (w50 - ha * 25)] = v.x;
            int w51 = w50 + 1;
            int hb = (w51 >= 25) ? 1 : 0;
            lds[it * IT + ((hb * 5 + c) * 5 + h) * 25 + (w51 - hb * 25)] = v.y;
        }
    }
    if (tid < 64) {
        int oc = tid & 31;
        if (tid < 32) {
            float inv = g1[oc] * rsqrtf(va1[oc] + BN_EPS);
            cst[oc]      = inv;
            cst[32 + oc] = be1[oc] - mu1[oc] * inv;
        } else {
            float inv = g2[oc] * rsqrtf(va2[oc] + BN_EPS);
            cst[64 + oc] = inv;
            cst[96 + oc] = be2[oc] - mu2[oc] * inv;
        }
    }
    __syncthreads();

    // ---- phase 0.5: stage bf16-RNE conv1 A panels (2 parity copies + halo) ----
    {
        unsigned* abf0 = (unsigned*)lds;
        for (int d = tid; d < 2 * ABF_PER_IT; d += 256) {
            int it = (d >= ABF_PER_IT) ? 1 : 0;
            int d2 = d - it * ABF_PER_IT;
            unsigned u = 0;
            if (d2 < 1800) {
                int R2 = d2 / 36, o = d2 - R2 * 36;
                int cp = (o >= 18) ? 1 : 0;
                int half = (R2 >= 25) ? 1 : 0;
                int ickh = R2 - half * 25;
                int e = 2 * o - (cp ? 37 : 0);
                const float* src = &lds[it * IT + (half * 25 + ickh) * 25];
                int p0 = e + 20; if (p0 >= 25) p0 -= 25; if (p0 >= 25) p0 -= 25;
                int p1 = e + 21; if (p1 >= 25) p1 -= 25; if (p1 >= 25) p1 -= 25;
                u = (unsigned)f2bf_rne(src[p0]) | ((unsigned)f2bf_rne(src[p1]) << 16);
            }
            abf0[it * IT + ATO + d2] = u;
        }
    }
    __syncthreads();

    // ---- phase 1: conv1 via MFMA 16x16x32 bf16 (A bf16-RNE, B=hi+lo) ----
    {
        const int wave = tid >> 6, lane = tid & 63;
        const int it = wave >> 1;
        const int Mtb = (wave & 1) * 2;
        const int quad = lane >> 4, m16 = lane & 15;
        const int kw0 = (quad & 1) * 8;
        const int ickh0 = quad >> 1;
        const unsigned* abf = (const unsigned*)lds;   // dword-indexed

        int dwb[2];
#pragma unroll
        for (int mt = 0; mt < 2; ++mt) {
            int mg = (Mtb + mt) * 16 + m16;
            int half = (mg >= 25) ? 1 : 0;
            int pos = mg - half * 25; pos = (pos > 24) ? 24 : pos;  // pad rows clamp
            int e0 = pos + kw0;
            int c = e0 & 1;
            int R2b = half * 25 + ickh0;
            dwb[mt] = it * IT + ATO + R2b * 36 + c * 18 + ((e0 + c) >> 1);
        }

        v4f zz = {0.f, 0.f, 0.f, 0.f};
        v4f acc[2][2];
        acc[0][0] = zz; acc[0][1] = zz; acc[1][0] = zz; acc[1][1] = zz;

        for (int Kt = 0; Kt < 13; ++Kt) {
            union { unsigned u[4]; short8 v; } af[2];
#pragma unroll
            for (int mt = 0; mt < 2; ++mt) {
                int base = dwb[mt] + Kt * 72;   // R2 advances by 2 per Kt
                af[mt].u[0] = abf[base + 0];
                af[mt].u[1] = abf[base + 1];
                af[mt].u[2] = abf[base + 2];
                af[mt].u[3] = abf[base + 3];
            }
#pragma unroll
            for (int nt = 0; nt < 2; ++nt) {
                const short8* ph = (const short8*)(ws16 + ((nt * 13 + Kt) * 64 + lane) * 8);
                const short8* pl = (const short8*)(ws16 + 13312 + ((nt * 13 + Kt) * 64 + lane) * 8);
                short8 bh = *ph;
                short8 bl = *pl;
#pragma unroll
                for (int mt = 0; mt < 2; ++mt) {
                    acc[mt][nt] = __builtin_amdgcn_mfma_f32_16x16x32_bf16(af[mt].v, bh, acc[mt][nt], 0, 0, 0);
                    acc[mt][nt] = __builtin_amdgcn_mfma_f32_16x16x32_bf16(af[mt].v, bl, acc[mt][nt], 0, 0, 0);
                }
            }
        }

        // epilogue: D col=oc-in-tile, row=quad*4+r. Write hbf k-major pair-packed
        // ushort idx: hi kd*132 + ch*2 + (pos&1); lo +2112. (xh dead; abf untouched.)
        float bias0 = b1[m16], bias1 = b1[16 + m16];
        unsigned short* U = (unsigned short*)(lds + it * IT);
#pragma unroll
        for (int mt = 0; mt < 2; ++mt) {
#pragma unroll
            for (int r = 0; r < 4; ++r) {
                int mg = (Mtb + mt) * 16 + quad * 4 + r;
                if (mg < 50) {
                    int half = (mg >= 25) ? 1 : 0;
                    int pos = mg - half * 25;
                    int kd = pos >> 1, par = pos & 1;
                    float v0 = acc[mt][0][r] + bias0;
                    float v1 = acc[mt][1][r] + bias1;
                    int ch0 = half * 32 + m16;
                    int ch1 = half * 32 + 16 + m16;
                    unsigned short h0 = f2bf_rne(v0);
                    unsigned short h1v = f2bf_rne(v1);
                    U[kd * 132 + ch0 * 2 + par] = h0;
                    U[2112 + kd * 132 + ch0 * 2 + par] = f2bf_rne(v0 - bf2f(h0));
                    U[kd * 132 + ch1 * 2 + par] = h1v;
                    U[2112 + kd * 132 + ch1 * 2 + par] = f2bf_rne(v1 - bf2f(h1v));
                }
            }
        }
    }
    __syncthreads();

    // ---- phase 2: layer-1 scores via MFMA Gram: S[m][n]=<H[m],H[n]> (K=25 pad 32)
    // frag dword i = hbf[(q*4+i)*66 + row]; mask k=24 pair high, k>24 zero.
    {
        const int wave = tid >> 6, lane = tid & 63;
        const int it = wave >> 1, half = wave & 1;
        const int m16 = lane & 15, q = lane >> 4;
        const unsigned* D = (const unsigned*)(lds + it * IT);
        short8 fh[2], fl[2];
#pragma unroll
        for (int t = 0; t < 2; ++t) {
            int row = half * 32 + t * 16 + m16;
            union { unsigned u[4]; short8 v; } H, L;
#pragma unroll
            for (int i = 0; i < 4; ++i) {
                int k0 = q * 8 + 2 * i;
                unsigned mh = D[(k0 >> 1) * 66 + row];
                unsigned ml = D[1056 + (k0 >> 1) * 66 + row];
                if (k0 == 24) { mh &= 0xFFFFu; ml &= 0xFFFFu; }
                if (k0 > 24)  { mh = 0u; ml = 0u; }
                H.u[i] = mh; L.u[i] = ml;
            }
            fh[t] = H.v; fl[t] = L.v;
        }
        v4f zz = {0.f, 0.f, 0.f, 0.f};
        v4f acc[2][2];
        acc[0][0] = zz; acc[0][1] = zz; acc[1][0] = zz; acc[1][1] = zz;
#pragma unroll
        for (int mt = 0; mt < 2; ++mt)
#pragma unroll
            for (int nt = 0; nt < 2; ++nt) {
                acc[mt][nt] = __builtin_amdgcn_mfma_f32_16x16x32_bf16(fh[mt], fh[nt], acc[mt][nt], 0, 0, 0);
                acc[mt][nt] = __builtin_amdgcn_mfma_f32_16x16x32_bf16(fh[mt], fl[nt], acc[mt][nt], 0, 0, 0);
                acc[mt][nt] = __builtin_amdgcn_mfma_f32_16x16x32_bf16(fl[mt], fh[nt], acc[mt][nt], 0, 0, 0);
            }
        // aT region [2112,4224) disjoint from hbf -> no internal barrier
        float* A = &lds[it * IT + ATO];
#pragma unroll
        for (int mt = 0; mt < 2; ++mt)
#pragma unroll
            for (int nt = 0; nt < 2; ++nt)
#pragma unroll
                for (int r = 0; r < 4; ++r) {
                    int m = mt * 16 + q * 4 + r;
                    int n = nt * 16 + m16;
                    float s = acc[mt][nt][r];
                    s = (s > 0.f) ? s : ALPHA * s;
                    A[(half * 32 + m) * 33 + n] = s;
                }
    }
    __syncthreads();

    // ---- phase 3: softmax over n; 128 rows x 2 lanes ----
    {
        int row = tid >> 1, q = tid & 1;
        int it = row >> 6, rm = row & 63;
        float* rp = &lds[it * IT + ATO + rm * 33];
        float ev[16];
        float mx = -INFINITY;
#pragma unroll
        for (int k = 0; k < 16; ++k) { ev[k] = rp[q + 2 * k]; mx = fmaxf(mx, ev[k]); }
        mx = fmaxf(mx, __shfl_xor(mx, 1));
        float s = 0.f;
#pragma unroll
        for (int k = 0; k < 16; ++k) { ev[k] = __expf(ev[k] - mx); s += ev[k]; }
        s += __shfl_xor(s, 1);
        float inv = 1.f / s;
#pragma unroll
        for (int k = 0; k < 16; ++k) rp[q + 2 * k] = ev[k] * inv;
    }
    __syncthreads();

    // ---- phase 4+5: (att @ h1) via MFMA, D[pos][n] -> bn1 -> pool (in-lane)
    //      -> relu -> pt (bf16 hi/lo, k-major by ic, for conv2)
    {
        const int wave = tid >> 6, lane = tid & 63;
        const int it = wave >> 1, half = wave & 1;
        const int m16 = lane & 15, q = lane >> 4;
        const unsigned short* U = (const unsigned short*)(lds + it * IT);
        const float* AT = &lds[it * IT + ATO];

        // A-frags: A[pos][k=m] = h1[ch=half*32+m][pos]; pos = mt*16 + m16
        short8 ah[2], al[2];
#pragma unroll
        for (int mt = 0; mt < 2; ++mt) {
            int pos = mt * 16 + m16;
            int kd = pos >> 1, par = pos & 1;
            union { unsigned u[4]; short8 v; } H, L;
#pragma unroll
            for (int i = 0; i < 4; ++i) {
                int ch = half * 32 + q * 8 + 2 * i;
                unsigned h0 = U[kd * 132 + ch * 2 + par];
                unsigned h1u = U[kd * 132 + (ch + 1) * 2 + par];
                unsigned l0 = U[2112 + kd * 132 + ch * 2 + par];
                unsigned l1 = U[2112 + kd * 132 + (ch + 1) * 2 + par];
                H.u[i] = h0 | (h1u << 16);
                L.u[i] = l0 | (l1 << 16);
            }
            ah[mt] = H.v; al[mt] = L.v;
        }
        // B-frags: B[k=m][n] = att from aT (f32 -> bf16 hi/lo once)
        short8 bh[2], bl[2];
#pragma unroll
        for (int nt = 0; nt < 2; ++nt) {
            union { unsigned u[4]; short8 v; } H, L;
#pragma unroll
            for (int i = 0; i < 4; ++i) {
                unsigned hh = 0, ll = 0;
#pragma unroll
                for (int t = 0; t < 2; ++t) {
                    int m = q * 8 + 2 * i + t;
                    float a = AT[(half * 32 + m) * 33 + nt * 16 + m16];
                    unsigned short hx = f2bf_rne(a);
                    hh |= ((unsigned)hx) << (16 * t);
                    ll |= ((unsigned)f2bf_rne(a - bf2f(hx))) << (16 * t);
                }
                H.u[i] = hh; L.u[i] = ll;
            }
            bh[nt] = H.v; bl[nt] = L.v;
        }
        v4f zz = {0.f, 0.f, 0.f, 0.f};
        v4f acc[2][2];
        acc[0][0] = zz; acc[0][1] = zz; acc[1][0] = zz; acc[1][1] = zz;
#pragma unroll
        for (int mt = 0; mt < 2; ++mt)
#pragma unroll
            for (int nt = 0; nt < 2; ++nt) {
                acc[mt][nt] = __builtin_amdgcn_mfma_f32_16x16x32_bf16(ah[mt], bh[nt], acc[mt][nt], 0, 0, 0);
                acc[mt][nt] = __builtin_amdgcn_mfma_f32_16x16x32_bf16(ah[mt], bl[nt], acc[mt][nt], 0, 0, 0);
                acc[mt][nt] = __builtin_amdgcn_mfma_f32_16x16x32_bf16(al[mt], bh[nt], acc[mt][nt], 0, 0, 0);
            }

        __syncthreads();   // all hbf reads done before pt overwrites the region

        // epilogue: pos = mt*16 + q*4 + r (r-pairs pool in-lane); n = nt*16+m16
        unsigned short* PT = (unsigned short*)(lds + it * IT) + half * 832;
#pragma unroll
        for (int mt = 0; mt < 2; ++mt)
#pragma unroll
            for (int nt = 0; nt < 2; ++nt) {
                int n = nt * 16 + m16;
                float inv = cst[n], sh = cst[32 + n];
#pragma unroll
                for (int rr = 0; rr < 2; ++rr) {
                    int pos0 = mt * 16 + q * 4 + rr * 2;
                    if (pos0 < 24) {
                        float v0 = acc[mt][nt][rr * 2] * inv + sh;
                        float v1 = acc[mt][nt][rr * 2 + 1] * inv + sh;
                        float p = fmaxf(fmaxf(v0, v1), 0.f);
                        int j = pos0 >> 1;
                        unsigned short h = f2bf_rne(p);
                        PT[(n >> 1) * 26 + j * 2 + (n & 1)] = h;
                        PT[416 + (n >> 1) * 26 + j * 2 + (n & 1)] = f2bf_rne(p - bf2f(h));
                    }
                }
            }
    }
    __syncthreads();

    // ---- phase 6: conv2 as 5 kw-split MFMA GEMMs (K=32=ic), A from pt (no conv) ----
    {
        const int wave = tid >> 6, lane = tid & 63;
        const int it = wave >> 1, half = wave & 1;
        const int m16 = lane & 15, q = lane >> 4;
        const unsigned* PTD = (const unsigned*)(lds + it * IT) + half * 416;

        v4f zz = {0.f, 0.f, 0.f, 0.f};
        v4f acc[2]; acc[0] = zz; acc[1] = zz;
#pragma unroll
        for (int kw = 0; kw < 5; ++kw) {
            int owr = m16 + kw - 2;
            if (owr < 0) owr += 12;
            if (owr >= 12) owr -= 12;
            union { unsigned u[4]; short8 v; } H, L;
#pragma unroll
            for (int i = 0; i < 4; ++i) {
                H.u[i] = PTD[(q * 4 + i) * 13 + owr];
                L.u[i] = PTD[208 + (q * 4 + i) * 13 + owr];
            }
#pragma unroll
            for (int nt = 0; nt < 2; ++nt) {
                const short8* ph = (const short8*)(ws16 + 26624 + ((kw * 2 + nt) * 64 + lane) * 8);
                const short8* pl = (const short8*)(ws16 + 31744 + ((kw * 2 + nt) * 64 + lane) * 8);
                short8 wbh = *ph, wbl = *pl;
                acc[nt] = __builtin_amdgcn_mfma_f32_16x16x32_bf16(H.v, wbh, acc[nt], 0, 0, 0);
                acc[nt] = __builtin_amdgcn_mfma_f32_16x16x32_bf16(H.v, wbl, acc[nt], 0, 0, 0);
                acc[nt] = __builtin_amdgcn_mfma_f32_16x16x32_bf16(L.v, wbh, acc[nt], 0, 0, 0);
            }
        }
        // epilogue: D[ow=q*4+r][oc=nt*16+m16]; write h2bf (dw 1056+, pair-packed by ow)
        // disjoint from pt [0,832) -> no internal barrier
        if (q < 3) {
            unsigned* H2 = (unsigned*)(lds + it * IT) + 1056;
#pragma unroll
            for (int nt = 0; nt < 2; ++nt) {
                float bias = b2[nt * 16 + m16];
                int ch = half * 32 + nt * 16 + m16;
#pragma unroll
                for (int rr = 0; rr < 2; ++rr) {
                    float v0 = acc[nt][rr * 2] + bias;
                    float v1 = acc[nt][rr * 2 + 1] + bias;
                    unsigned short h0 = f2bf_rne(v0), h1u = f2bf_rne(v1);
                    H2[(q * 2 + rr) * 66 + ch] = (unsigned)h0 | ((unsigned)h1u << 16);
                    H2[528 + (q * 2 + rr) * 66 + ch] =
                        (unsigned)f2bf_rne(v0 - bf2f(h0)) |
                        ((unsigned)f2bf_rne(v1 - bf2f(h1u)) << 16);
                }
            }
        }
    }
    __syncthreads();

    // ---- phase 7: layer-2 scores via MFMA: S[m][n]=<H2[1-half][m],H2[half][n]>, K=12 pad 32
    {
        const int wave = tid >> 6, lane = tid & 63;
        const int it = wave >> 1, half = wave & 1;
        const int m16 = lane & 15, q = lane >> 4;
        const unsigned* D = (const unsigned*)(lds + it * IT) + 1056;
        short8 ah[2], al[2], bh[2], bl[2];
#pragma unroll
        for (int t = 0; t < 2; ++t) {
            int rowA = (1 - half) * 32 + t * 16 + m16;
            int rowB = half * 32 + t * 16 + m16;
            union { unsigned u[4]; short8 v; } HA, LA, HB, LB;
#pragma unroll
            for (int i = 0; i < 4; ++i) {
                int k0 = q * 8 + 2 * i;
                unsigned a_h = D[(k0 >> 1) * 66 + rowA];
                unsigned a_l = D[528 + (k0 >> 1) * 66 + rowA];
                unsigned b_h = D[(k0 >> 1) * 66 + rowB];
                unsigned b_l = D[528 + (k0 >> 1) * 66 + rowB];
                if (k0 > 10) { a_h = 0u; a_l = 0u; b_h = 0u; b_l = 0u; }
                HA.u[i] = a_h; LA.u[i] = a_l; HB.u[i] = b_h; LB.u[i] = b_l;
            }
            ah[t] = HA.v; al[t] = LA.v; bh[t] = HB.v; bl[t] = LB.v;
        }
        v4f zz = {0.f, 0.f, 0.f, 0.f};
        v4f acc[2][2];
        acc[0][0] = zz; acc[0][1] = zz; acc[1][0] = zz; acc[1][1] = zz;
#pragma unroll
        for (int mt = 0; mt < 2; ++mt)
#pragma unroll
            for (int nt = 0; nt < 2; ++nt) {
                acc[mt][nt] = __builtin_amdgcn_mfma_f32_16x16x32_bf16(ah[mt], bh[nt], acc[mt][nt], 0, 0, 0);
                acc[mt][nt] = __builtin_amdgcn_mfma_f32_16x16x32_bf16(ah[mt], bl[nt], acc[mt][nt], 0, 0, 0);
                acc[mt][nt] = __builtin_amdgcn_mfma_f32_16x16x32_bf16(al[mt], bh[nt], acc[mt][nt], 0, 0, 0);
            }
        // aT2 region disjoint from h2bf -> no internal barrier
        float* A = &lds[it * IT + ATO];
#pragma unroll
        for (int mt = 0; mt < 2; ++mt)
#pragma unroll
            for (int nt = 0; nt < 2; ++nt)
#pragma unroll
                for (int r = 0; r < 4; ++r) {
                    int m = mt * 16 + q * 4 + r;
                    int n = nt * 16 + m16;
                    float s = acc[mt][nt][r];
                    s = (s > 0.f) ? s : ALPHA * s;
                    A[(half * 32 + m) * 33 + n] = s;
                }
    }
    __syncthreads();

    // ---- phase 8: softmax ----
    {
        int row = tid >> 1, q = tid & 1;
        int it = row >> 6, rm = row & 63;
        float* rp = &lds[it * IT + ATO + rm * 33];
        float ev[16];
        float mx = -INFINITY;
#pragma unroll
        for (int k = 0; k < 16; ++k) { ev[k] = rp[q + 2 * k]; mx = fmaxf(mx, ev[k]); }
        mx = fmaxf(mx, __shfl_xor(mx, 1));
        float s = 0.f;
#pragma unroll
        for (int k = 0; k < 16; ++k) { ev[k] = __expf(ev[k] - mx); s += ev[k]; }
        s += __shfl_xor(s, 1);
        float inv = 1.f / s;
#pragma unroll
        for (int k = 0; k < 16; ++k) rp[q + 2 * k] = ev[k] * inv;
    }
    __syncthreads();

    // ---- phase 9+10: (att2 @ h2) via MFMA, D[pos][n] -> bn2 -> pool -> relu -> p2f
    {
        const int wave = tid >> 6, lane = tid & 63;
        const int it = wave >> 1, half = wave & 1;
        const int m16 = lane & 15, q = lane >> 4;
        const unsigned short* U = (const unsigned short*)(lds + it * IT);
        const float* AT = &lds[it * IT + ATO];

        // A-frag: A[pos=m16][k=m] = h2[ch=half*32+m][pos] from h2bf (ushort base 2112/3168)
        int kd = m16 >> 1, par = m16 & 1;
        union { unsigned u[4]; short8 v; } HA, LA;
#pragma unroll
        for (int i = 0; i < 4; ++i) {
            int ch = half * 32 + q * 8 + 2 * i;
            unsigned h0 = U[2112 + kd * 132 + ch * 2 + par];
            unsigned h1u = U[2112 + kd * 132 + (ch + 1) * 2 + par];
            unsigned l0 = U[3168 + kd * 132 + ch * 2 + par];
            unsigned l1 = U[3168 + kd * 132 + (ch + 1) * 2 + par];
            HA.u[i] = h0 | (h1u << 16);
            LA.u[i] = l0 | (l1 << 16);
        }
        // B-frags: att2 rows -> bf16 hi/lo
        short8 bh[2], bl[2];
#pragma unroll
        for (int nt = 0; nt < 2; ++nt) {
            union { unsigned u[4]; short8 v; } H, L;
#pragma unroll
            for (int i = 0; i < 4; ++i) {
                unsigned hh = 0, ll = 0;
#pragma unroll
                for (int t = 0; t < 2; ++t) {
                    int m = q * 8 + 2 * i + t;
                    float a = AT[(half * 32 + m) * 33 + nt * 16 + m16];
                    unsigned short hx = f2bf_rne(a);
                    hh |= ((unsigned)hx) << (16 * t);
                    ll |= ((unsigned)f2bf_rne(a - bf2f(hx))) << (16 * t);
                }
                H.u[i] = hh; L.u[i] = ll;
            }
            bh[nt] = H.v; bl[nt] = L.v;
        }
        v4f zz = {0.f, 0.f, 0.f, 0.f};
        v4f acc[2]; acc[0] = zz; acc[1] = zz;
#pragma unroll
        for (int nt = 0; nt < 2; ++nt) {
            acc[nt] = __builtin_amdgcn_mfma_f32_16x16x32_bf16(HA.v, bh[nt], acc[nt], 0, 0, 0);
            acc[nt] = __builtin_amdgcn_mfma_f32_16x16x32_bf16(HA.v, bl[nt], acc[nt], 0, 0, 0);
            acc[nt] = __builtin_amdgcn_mfma_f32_16x16x32_bf16(LA.v, bh[nt], acc[nt], 0, 0, 0);
        }
        // epilogue: D[pos=q*4+r][n=nt*16+m16]; p2f writes disjoint -> no barrier
        if (q < 3) {
#pragma unroll
            for (int nt = 0; nt < 2; ++nt) {
                int n = nt * 16 + m16;
                float inv = cst[64 + n], sh = cst[96 + n];
#pragma unroll
                for (int rr = 0; rr < 2; ++rr) {
                    int j = q * 2 + rr;
                    float v0 = acc[nt][rr * 2] * inv + sh;
                    float v1 = acc[nt][rr * 2 + 1] * inv + sh;
                    lds[it * IT + P2O + n * 12 + half * 6 + j] =
                        fmaxf(fmaxf(v0, v1), 0.f);
                }
            }
        }
    }
    __syncthreads();

    // ---- phase 11: linear 384 -> 13, both items; float4 dot ----
    if (tid < 208) {
        int s8 = tid & 7;
        int rest = tid >> 3;
        int it = (rest >= 13) ? 1 : 0;
        int o = rest - it * 13;
        const float4* wv4 = (const float4*)(lw + o * 384 + s8 * 48);
        const float4* fv4 = (const float4*)&lds[it * IT + P2O + s8 * 48];
        float s = 0.f;
#pragma unroll
        for (int i = 0; i < 12; ++i) {
            float4 w4 = wv4[i];
            float4 f4 = fv4[i];
            s += f4.x * w4.x + f4.y * w4.y + f4.z * w4.z + f4.w * w4.w;
        }
        s += __shfl_down(s, 4, 8);
        s += __shfl_down(s, 2, 8);
        s += __shfl_down(s, 1, 8);
        if (s8 == 0) out[(size_t)(b0 + it) * 13 + o] = s + lb[o];
    }
}

extern "C" void kernel_launch(void* const* d_in, const int* in_sizes, int n_in,
                              void* d_out, int out_size, void* d_ws, size_t ws_size,
                              hipStream_t stream) {
    const float* x   = (const float*)d_in[0];
    const float* w1  = (const float*)d_in[1];
    const float* b1  = (const float*)d_in[2];
    const float* g1  = (const float*)d_in[3];
    const float* be1 = (const float*)d_in[4];
    const float* mu1 = (const float*)d_in[5];
    const float* va1 = (const float*)d_in[6];
    const float* w2  = (const float*)d_in[7];
    const float* b2  = (const float*)d_in[8];
    const float* g2  = (const float*)d_in[9];
    const float* be2 = (const float*)d_in[10];
    const float* mu2 = (const float*)d_in[11];
    const float* va2 = (const float*)d_in[12];
    const float* lw  = (const float*)d_in[13];
    const float* lb  = (const float*)d_in[14];
    float* out = (float*)d_out;
    unsigned short* ws16 = (unsigned short*)d_ws;

    // pack conv1 + conv2 weights into MFMA B-fragments (hi/lo bf16), 73.7 KB in d_ws
    prep_kernel<<<9, 256, 0, stream>>>(w1, w2, ws16);

    int B = in_sizes[0] / 1250;  // 16384
    gcn_kernel<<<B / 2, 256, 0, stream>>>(x, w1, b1, g1, be1, mu1, va1,
                                          w2, b2, g2, be2, mu2, va2, lw, lb,
                                          ws16, out);
}

// Round 5
// 290.300 us; speedup vs baseline: 1.6271x; 1.0495x over previous
//
#include <hip/hip_runtime.h>
#include <math.h>

#define ALPHA 0.2f
#define BN_EPS 1e-5f

typedef __attribute__((ext_vector_type(8))) short short8;
typedef __attribute__((ext_vector_type(4))) float v4f;

// ---- bf16 bit helpers (RNE) ----
__device__ __forceinline__ unsigned short f2bf_rne(float f) {
    union { float f; unsigned u; } x; x.f = f;
    unsigned r = x.u + 0x7FFFu + ((x.u >> 16) & 1u);
    return (unsigned short)(r >> 16);
}
__device__ __forceinline__ float bf2f(unsigned short h) {
    union { float f; unsigned u; } x; x.u = ((unsigned)h) << 16;
    return x.f;
}
// packed f32x2 -> bf16x2 (a0 -> low16). Rounding mode of HW cvt_pk is
// irrelevant for hi/lo pairs: lo is computed against the actual hi.
__device__ __forceinline__ unsigned cvtpk_bf16(float a0, float a1) {
    unsigned r;
    asm("v_cvt_pk_bf16_f32 %0, %1, %2" : "=v"(r) : "v"(a0), "v"(a1));
    return r;
}
__device__ __forceinline__ void hilo_pair(float a0, float a1, unsigned& hp, unsigned& lp) {
    hp = cvtpk_bf16(a0, a1);
    union { unsigned u; float f; } c0, c1;
    c0.u = hp << 16; c1.u = hp & 0xFFFF0000u;
    lp = cvtpk_bf16(a0 - c0.f, a1 - c1.f);
}
// ((hi:lo) >> sh) & 0xffffffff, sh in {0,16}
__device__ __forceinline__ unsigned funnel16(unsigned hi, unsigned lo, int sh) {
    return (unsigned)((((unsigned long long)hi << 32) | lo) >> sh);
}

// ======== prep kernel: pack conv1 + conv2 weights as MFMA B-fragments ========
// conv1: K-order k' = ickh*16 + kw (kw 0..15, pad>=11 zero; ickh 0..25, pad 25 zero).
//   Kt = k'/32 in [0,13). Slot s = (Nt*13+Kt)*64+lane holds 8 ushorts:
//   elem j <-> B[k'=Kt*32+(lane>>4)*8+j][oc=Nt*16+(lane&15)].
//   hi at ws16[0..13312), lo at ws16[13312..26624).
// conv2 (kw-split, 5 GEMMs of K=32=ic): slot s2 = ((kw*2+nt)*64+lane):
//   elem j <-> B_kw[ic=(lane>>4)*8+j][oc=nt*16+(lane&15)] = w2[oc][ic][kw].
//   hi at ws16[26624..31744), lo at ws16[31744..36864).
__global__ __launch_bounds__(256) void prep_kernel(const float* __restrict__ w1,
                                                   const float* __restrict__ w2,
                                                   unsigned short* __restrict__ ws16) {
    int s = blockIdx.x * 256 + threadIdx.x;
    if (s < 1664) {
        int lane = s & 63;
        int ktnt = s >> 6;           // 0..25
        int Kt = ktnt % 13;
        int Nt = ktnt / 13;
        int oc = Nt * 16 + (lane & 15);
        int quad = lane >> 4;
        for (int j = 0; j < 8; ++j) {
            int kp = Kt * 32 + quad * 8 + j;
            int kw = kp & 15, ickh = kp >> 4;
            float w = 0.f;
            if (kw < 11 && ickh < 25) w = w1[oc * 275 + ickh * 11 + kw];
            unsigned short h = f2bf_rne(w);
            ws16[s * 8 + j] = h;
            ws16[13312 + s * 8 + j] = f2bf_rne(w - bf2f(h));
        }
    } else if (s < 2304) {
        int s2 = s - 1664;
        int lane = s2 & 63;
        int ktnt = s2 >> 6;          // 0..9 = kw*2+nt
        int kw = ktnt >> 1;
        int nt = ktnt & 1;
        int oc = nt * 16 + (lane & 15);
        int quad = lane >> 4;
        for (int j = 0; j < 8; ++j) {
            int ic = quad * 8 + j;
            float w = w2[oc * 160 + ic * 5 + kw];
            unsigned short h = f2bf_rne(w);
            ws16[26624 + s2 * 8 + j] = h;
            ws16[31744 + s2 * 8 + j] = f2bf_rne(w - bf2f(h));
        }
    }
}

// ======== main kernel ========
// Per-item LDS map (dwords, stride IT=3848):
//  [0,858)    : hbf hi (kd*66+ch; kd=pos>>1 0..12) ph1epi..ph4+5;
//               pt [0,832) ph4+5epi..ph6;  p2f f32 [0,384) ph9+10epi..ph11
//  [858,1716) : hbf lo ph1epi..ph4+5;
//               h2bf hi [858,1254) + lo [1254,1650) ph6epi..ph9+10
//  [1716,3828): xb bf16 halo'd input, 51 rows x 21dw (row 50 zeroed) ph0..ph1;
//               aT/aT2 f32 [64][33] ph2epi.. / ph7epi..
// cst @7696 [4][32]. Total 7824 dw = 31296 B -> 5 blocks/CU.
#define IT 3848
#define XBO 1716
#define ATO 1716
#define CSTO 7696
#define LDS_TOTAL (7696 + 128)

__global__ __launch_bounds__(256, 5) void gcn_kernel(
    const float* __restrict__ x,
    const float* __restrict__ w1, const float* __restrict__ b1,
    const float* __restrict__ g1, const float* __restrict__ be1,
    const float* __restrict__ mu1, const float* __restrict__ va1,
    const float* __restrict__ w2, const float* __restrict__ b2,
    const float* __restrict__ g2, const float* __restrict__ be2,
    const float* __restrict__ mu2, const float* __restrict__ va2,
    const float* __restrict__ lw, const float* __restrict__ lb,
    const unsigned short* __restrict__ ws16,
    float* __restrict__ out)
{
    __shared__ float lds[LDS_TOTAL];
    float* cst = lds + CSTO;

    const int tid = threadIdx.x;
    const int b0  = blockIdx.x * 2;

    // ---- phase 0: load 2 items as float2 -> bf16 halo'd xb rows; BN consts ----
    // halo index hx in [0,40): value = x[w=(hx-5) mod 25]; main hx=5+w,
    // left halo hx=w-20 (w>=20), right halo hx=30+w (w<=9). Row stride 42 us.
    {
        const float2* xg2 = (const float2*)(x + (size_t)b0 * 1250);
        for (int i2 = tid; i2 < 1250; i2 += 256) {
            float2 v = xg2[i2];
            int i = 2 * i2;
            int it = (i >= 1250) ? 1 : 0;
            int j = i - it * 1250;
            unsigned short* XU = (unsigned short*)(lds + it * IT + XBO);
            {
                int c = j / 250; int r = j - c * 250;
                int h = r / 50;  int w50 = r - h * 50;
                int ha = (w50 >= 25) ? 1 : 0;
                int w = w50 - ha * 25;
                int base = (ha * 25 + c * 5 + h) * 42;
                unsigned short u = f2bf_rne(v.x);
                XU[base + 5 + w] = u;
                if (w >= 20) XU[base + w - 20] = u;
                if (w <= 9)  XU[base + 30 + w] = u;
            }
            {
                int j1 = j + 1;
                int c = j1 / 250; int r = j1 - c * 250;
                int h = r / 50;  int w51 = r - h * 50;
                int hb = (w51 >= 25) ? 1 : 0;
                int w = w51 - hb * 25;
                int base = (hb * 25 + c * 5 + h) * 42;
                unsigned short u = f2bf_rne(v.y);
                XU[base + 5 + w] = u;
                if (w >= 20) XU[base + w - 20] = u;
                if (w <= 9)  XU[base + 30 + w] = u;
            }
        }
        // zero pad row 50 (read when ickh==25; B=0 there but NaN*0=NaN)
        if (tid < 42) {
            int itz = (tid >= 21) ? 1 : 0;
            lds[itz * IT + XBO + 1050 + (tid - itz * 21)] = 0.f;
        }
    }
    if (tid < 64) {
        int oc = tid & 31;
        if (tid < 32) {
            float inv = g1[oc] * rsqrtf(va1[oc] + BN_EPS);
            cst[oc]      = inv;
            cst[32 + oc] = be1[oc] - mu1[oc] * inv;
        } else {
            float inv = g2[oc] * rsqrtf(va2[oc] + BN_EPS);
            cst[64 + oc] = inv;
            cst[96 + oc] = be2[oc] - mu2[oc] * inv;
        }
    }
    __syncthreads();

    // ---- phase 1: conv1 via MFMA 16x16x32 bf16 (A direct from xb, B=hi+lo) ----
    {
        const int wave = tid >> 6, lane = tid & 63;
        const int it = wave >> 1;
        const int Mtb = (wave & 1) * 2;
        const int quad = lane >> 4, m16 = lane & 15;
        const int kw0 = (quad & 1) * 8;
        const int ickh0 = quad >> 1;
        const unsigned* XD = (const unsigned*)(lds + it * IT + XBO);

        int ub[2], sh[2];
#pragma unroll
        for (int mt = 0; mt < 2; ++mt) {
            int mg = (Mtb + mt) * 16 + m16;
            int half = (mg >= 25) ? 1 : 0;
            int pos = mg - half * 25; pos = (pos > 24) ? 24 : pos;  // pad rows clamp
            int ux = (half * 25 + ickh0) * 42 + pos + kw0;
            ub[mt] = ux >> 1;
            sh[mt] = (ux & 1) << 4;
        }

        v4f zz = {0.f, 0.f, 0.f, 0.f};
        v4f acc[2][2];
        acc[0][0] = zz; acc[0][1] = zz; acc[1][0] = zz; acc[1][1] = zz;

        for (int Kt = 0; Kt < 13; ++Kt) {
            union { unsigned u[4]; short8 v; } af[2];
#pragma unroll
            for (int mt = 0; mt < 2; ++mt) {
                int b = ub[mt] + Kt * 42;      // ickh advances 2 rows per Kt
                unsigned d0 = XD[b + 0], d1 = XD[b + 1], d2 = XD[b + 2];
                unsigned d3 = XD[b + 3], d4 = XD[b + 4];
                af[mt].u[0] = funnel16(d1, d0, sh[mt]);
                af[mt].u[1] = funnel16(d2, d1, sh[mt]);
                af[mt].u[2] = funnel16(d3, d2, sh[mt]);
                af[mt].u[3] = funnel16(d4, d3, sh[mt]);
            }
#pragma unroll
            for (int nt = 0; nt < 2; ++nt) {
                const short8* ph = (const short8*)(ws16 + ((nt * 13 + Kt) * 64 + lane) * 8);
                const short8* pl = (const short8*)(ws16 + 13312 + ((nt * 13 + Kt) * 64 + lane) * 8);
                short8 bh = *ph;
                short8 bl = *pl;
#pragma unroll
                for (int mt = 0; mt < 2; ++mt) {
                    acc[mt][nt] = __builtin_amdgcn_mfma_f32_16x16x32_bf16(af[mt].v, bh, acc[mt][nt], 0, 0, 0);
                    acc[mt][nt] = __builtin_amdgcn_mfma_f32_16x16x32_bf16(af[mt].v, bl, acc[mt][nt], 0, 0, 0);
                }
            }
        }

        // epilogue: hbf k-major pair-packed; hi ushort kd*132+ch*2+par, lo +1716.
        // xb ([1716+)) and hbf ([0,1716)) disjoint -> no internal barrier.
        float bias0 = b1[m16], bias1 = b1[16 + m16];
        unsigned short* U = (unsigned short*)(lds + it * IT);
#pragma unroll
        for (int mt = 0; mt < 2; ++mt) {
#pragma unroll
            for (int r = 0; r < 4; ++r) {
                int mg = (Mtb + mt) * 16 + quad * 4 + r;
                if (mg < 50) {
                    int half = (mg >= 25) ? 1 : 0;
                    int pos = mg - half * 25;
                    int kd = pos >> 1, par = pos & 1;
                    float v0 = acc[mt][0][r] + bias0;
                    float v1 = acc[mt][1][r] + bias1;
                    int ch0 = half * 32 + m16;
                    int ch1 = half * 32 + 16 + m16;
                    unsigned short h0 = f2bf_rne(v0);
                    unsigned short h1v = f2bf_rne(v1);
                    U[kd * 132 + ch0 * 2 + par] = h0;
                    U[1716 + kd * 132 + ch0 * 2 + par] = f2bf_rne(v0 - bf2f(h0));
                    U[kd * 132 + ch1 * 2 + par] = h1v;
                    U[1716 + kd * 132 + ch1 * 2 + par] = f2bf_rne(v1 - bf2f(h1v));
                }
            }
        }
    }
    __syncthreads();

    // ---- phase 2: layer-1 scores via MFMA Gram: S[m][n]=<H[m],H[n]> (K=25 pad 32)
    {
        const int wave = tid >> 6, lane = tid & 63;
        const int it = wave >> 1, half = wave & 1;
        const int m16 = lane & 15, q = lane >> 4;
        const unsigned* D = (const unsigned*)(lds + it * IT);
        short8 fh[2], fl[2];
#pragma unroll
        for (int t = 0; t < 2; ++t) {
            int row = half * 32 + t * 16 + m16;
            union { unsigned u[4]; short8 v; } H, L;
#pragma unroll
            for (int i = 0; i < 4; ++i) {
                int k0 = q * 8 + 2 * i;
                unsigned mh = D[(k0 >> 1) * 66 + row];
                unsigned ml = D[858 + (k0 >> 1) * 66 + row];
                if (k0 == 24) { mh &= 0xFFFFu; ml &= 0xFFFFu; }
                if (k0 > 24)  { mh = 0u; ml = 0u; }
                H.u[i] = mh; L.u[i] = ml;
            }
            fh[t] = H.v; fl[t] = L.v;
        }
        v4f zz = {0.f, 0.f, 0.f, 0.f};
        v4f acc[2][2];
        acc[0][0] = zz; acc[0][1] = zz; acc[1][0] = zz; acc[1][1] = zz;
#pragma unroll
        for (int mt = 0; mt < 2; ++mt)
#pragma unroll
            for (int nt = 0; nt < 2; ++nt) {
                acc[mt][nt] = __builtin_amdgcn_mfma_f32_16x16x32_bf16(fh[mt], fh[nt], acc[mt][nt], 0, 0, 0);
                acc[mt][nt] = __builtin_amdgcn_mfma_f32_16x16x32_bf16(fh[mt], fl[nt], acc[mt][nt], 0, 0, 0);
                acc[mt][nt] = __builtin_amdgcn_mfma_f32_16x16x32_bf16(fl[mt], fh[nt], acc[mt][nt], 0, 0, 0);
            }
        // aT [1716,3828) disjoint from hbf -> no internal barrier (xb is dead)
        float* A = &lds[it * IT + ATO];
#pragma unroll
        for (int mt = 0; mt < 2; ++mt)
#pragma unroll
            for (int nt = 0; nt < 2; ++nt)
#pragma unroll
                for (int r = 0; r < 4; ++r) {
                    int m = mt * 16 + q * 4 + r;
                    int n = nt * 16 + m16;
                    float s = acc[mt][nt][r];
                    s = (s > 0.f) ? s : ALPHA * s;
                    A[(half * 32 + m) * 33 + n] = s;
                }
    }
    __syncthreads();

    // ---- phase 3: softmax over n; 128 rows x 2 lanes ----
    {
        int row = tid >> 1, q = tid & 1;
        int it = row >> 6, rm = row & 63;
        float* rp = &lds[it * IT + ATO + rm * 33];
        float ev[16];
        float mx = -INFINITY;
#pragma unroll
        for (int k = 0; k < 16; ++k) { ev[k] = rp[q + 2 * k]; mx = fmaxf(mx, ev[k]); }
        mx = fmaxf(mx, __shfl_xor(mx, 1));
        float s = 0.f;
#pragma unroll
        for (int k = 0; k < 16; ++k) { ev[k] = __expf(ev[k] - mx); s += ev[k]; }
        s += __shfl_xor(s, 1);
        float inv = 1.f / s;
#pragma unroll
        for (int k = 0; k < 16; ++k) rp[q + 2 * k] = ev[k] * inv;
    }
    __syncthreads();

    // ---- phase 4+5: (att @ h1) via MFMA, D[pos][n] -> bn1 -> pool (in-lane)
    //      -> relu -> pt (bf16 hi/lo, k-major by ic, for conv2)
    {
        const int wave = tid >> 6, lane = tid & 63;
        const int it = wave >> 1, half = wave & 1;
        const int m16 = lane & 15, q = lane >> 4;
        const unsigned short* U = (const unsigned short*)(lds + it * IT);
        const float* AT = &lds[it * IT + ATO];

        // A-frags: A[pos][k=m] = h1[ch=half*32+m][pos]; pos = mt*16 + m16
        short8 ah[2], al[2];
#pragma unroll
        for (int mt = 0; mt < 2; ++mt) {
            int pos = mt * 16 + m16;
            int kd = pos >> 1, par = pos & 1;
            union { unsigned u[4]; short8 v; } H, L;
#pragma unroll
            for (int i = 0; i < 4; ++i) {
                int ch = half * 32 + q * 8 + 2 * i;
                unsigned h0 = U[kd * 132 + ch * 2 + par];
                unsigned h1u = U[kd * 132 + (ch + 1) * 2 + par];
                unsigned l0 = U[1716 + kd * 132 + ch * 2 + par];
                unsigned l1 = U[1716 + kd * 132 + (ch + 1) * 2 + par];
                H.u[i] = h0 | (h1u << 16);
                L.u[i] = l0 | (l1 << 16);
            }
            ah[mt] = H.v; al[mt] = L.v;
        }
        // B-frags: B[k=m][n] = att from aT (f32 -> bf16 hi/lo via cvt_pk)
        short8 bh[2], bl[2];
#pragma unroll
        for (int nt = 0; nt < 2; ++nt) {
            union { unsigned u[4]; short8 v; } H, L;
#pragma unroll
            for (int i = 0; i < 4; ++i) {
                int m = q * 8 + 2 * i;
                float a0 = AT[(half * 32 + m) * 33 + nt * 16 + m16];
                float a1 = AT[(half * 32 + m + 1) * 33 + nt * 16 + m16];
                unsigned hp, lp;
                hilo_pair(a0, a1, hp, lp);
                H.u[i] = hp; L.u[i] = lp;
            }
            bh[nt] = H.v; bl[nt] = L.v;
        }
        v4f zz = {0.f, 0.f, 0.f, 0.f};
        v4f acc[2][2];
        acc[0][0] = zz; acc[0][1] = zz; acc[1][0] = zz; acc[1][1] = zz;
#pragma unroll
        for (int mt = 0; mt < 2; ++mt)
#pragma unroll
            for (int nt = 0; nt < 2; ++nt) {
                acc[mt][nt] = __builtin_amdgcn_mfma_f32_16x16x32_bf16(ah[mt], bh[nt], acc[mt][nt], 0, 0, 0);
                acc[mt][nt] = __builtin_amdgcn_mfma_f32_16x16x32_bf16(ah[mt], bl[nt], acc[mt][nt], 0, 0, 0);
                acc[mt][nt] = __builtin_amdgcn_mfma_f32_16x16x32_bf16(al[mt], bh[nt], acc[mt][nt], 0, 0, 0);
            }

        __syncthreads();   // all hbf reads done before pt overwrites the region

        // epilogue: pos = mt*16 + q*4 + r (r-pairs pool in-lane); n = nt*16+m16
        unsigned short* PT = (unsigned short*)(lds + it * IT) + half * 832;
#pragma unroll
        for (int mt = 0; mt < 2; ++mt)
#pragma unroll
            for (int nt = 0; nt < 2; ++nt) {
                int n = nt * 16 + m16;
                float inv = cst[n], sh = cst[32 + n];
#pragma unroll
                for (int rr = 0; rr < 2; ++rr) {
                    int pos0 = mt * 16 + q * 4 + rr * 2;
                    if (pos0 < 24) {
                        float v0 = acc[mt][nt][rr * 2] * inv + sh;
                        float v1 = acc[mt][nt][rr * 2 + 1] * inv + sh;
                        float p = fmaxf(fmaxf(v0, v1), 0.f);
                        int j = pos0 >> 1;
                        unsigned short h = f2bf_rne(p);
                        PT[(n >> 1) * 26 + j * 2 + (n & 1)] = h;
                        PT[416 + (n >> 1) * 26 + j * 2 + (n & 1)] = f2bf_rne(p - bf2f(h));
                    }
                }
            }
    }
    __syncthreads();

    // ---- phase 6: conv2 as 5 kw-split MFMA GEMMs (K=32=ic), A from pt ----
    {
        const int wave = tid >> 6, lane = tid & 63;
        const int it = wave >> 1, half = wave & 1;
        const int m16 = lane & 15, q = lane >> 4;
        const unsigned* PTD = (const unsigned*)(lds + it * IT) + half * 416;

        v4f zz = {0.f, 0.f, 0.f, 0.f};
        v4f acc[2]; acc[0] = zz; acc[1] = zz;
#pragma unroll
        for (int kw = 0; kw < 5; ++kw) {
            int owr = m16 + kw - 2;
            if (owr < 0) owr += 12;
            if (owr >= 12) owr -= 12;
            union { unsigned u[4]; short8 v; } H, L;
#pragma unroll
            for (int i = 0; i < 4; ++i) {
                H.u[i] = PTD[(q * 4 + i) * 13 + owr];
                L.u[i] = PTD[208 + (q * 4 + i) * 13 + owr];
            }
#pragma unroll
            for (int nt = 0; nt < 2; ++nt) {
                const short8* ph = (const short8*)(ws16 + 26624 + ((kw * 2 + nt) * 64 + lane) * 8);
                const short8* pl = (const short8*)(ws16 + 31744 + ((kw * 2 + nt) * 64 + lane) * 8);
                short8 wbh = *ph, wbl = *pl;
                acc[nt] = __builtin_amdgcn_mfma_f32_16x16x32_bf16(H.v, wbh, acc[nt], 0, 0, 0);
                acc[nt] = __builtin_amdgcn_mfma_f32_16x16x32_bf16(H.v, wbl, acc[nt], 0, 0, 0);
                acc[nt] = __builtin_amdgcn_mfma_f32_16x16x32_bf16(L.v, wbh, acc[nt], 0, 0, 0);
            }
        }
        // epilogue: D[ow=q*4+r][oc]; h2bf hi dw 858+kd*66+ch, lo +396.
        // h2bf overlays dead hbf-lo; disjoint from pt [0,832) -> no barrier.
        if (q < 3) {
            unsigned* H2 = (unsigned*)(lds + it * IT) + 858;
#pragma unroll
            for (int nt = 0; nt < 2; ++nt) {
                float bias = b2[nt * 16 + m16];
                int ch = half * 32 + nt * 16 + m16;
#pragma unroll
                for (int rr = 0; rr < 2; ++rr) {
                    float v0 = acc[nt][rr * 2] + bias;
                    float v1 = acc[nt][rr * 2 + 1] + bias;
                    unsigned hp, lp;
                    hilo_pair(v0, v1, hp, lp);
                    H2[(q * 2 + rr) * 66 + ch] = hp;
                    H2[396 + (q * 2 + rr) * 66 + ch] = lp;
                }
            }
        }
    }
    __syncthreads();

    // ---- phase 7: layer-2 scores via MFMA: S[m][n]=<H2[1-half][m],H2[half][n]>, K=12 pad 32
    {
        const int wave = tid >> 6, lane = tid & 63;
        const int it = wave >> 1, half = wave & 1;
        const int m16 = lane & 15, q = lane >> 4;
        const unsigned* D = (const unsigned*)(lds + it * IT) + 858;
        short8 ah[2], al[2], bh[2], bl[2];
#pragma unroll
        for (int t = 0; t < 2; ++t) {
            int rowA = (1 - half) * 32 + t * 16 + m16;
            int rowB = half * 32 + t * 16 + m16;
            union { unsigned u[4]; short8 v; } HA, LA, HB, LB;
#pragma unroll
            for (int i = 0; i < 4; ++i) {
                int k0 = q * 8 + 2 * i;
                unsigned a_h = D[(k0 >> 1) * 66 + rowA];
                unsigned a_l = D[396 + (k0 >> 1) * 66 + rowA];
                unsigned b_h = D[(k0 >> 1) * 66 + rowB];
                unsigned b_l = D[396 + (k0 >> 1) * 66 + rowB];
                if (k0 > 10) { a_h = 0u; a_l = 0u; b_h = 0u; b_l = 0u; }
                HA.u[i] = a_h; LA.u[i] = a_l; HB.u[i] = b_h; LB.u[i] = b_l;
            }
            ah[t] = HA.v; al[t] = LA.v; bh[t] = HB.v; bl[t] = LB.v;
        }
        v4f zz = {0.f, 0.f, 0.f, 0.f};
        v4f acc[2][2];
        acc[0][0] = zz; acc[0][1] = zz; acc[1][0] = zz; acc[1][1] = zz;
#pragma unroll
        for (int mt = 0; mt < 2; ++mt)
#pragma unroll
            for (int nt = 0; nt < 2; ++nt) {
                acc[mt][nt] = __builtin_amdgcn_mfma_f32_16x16x32_bf16(ah[mt], bh[nt], acc[mt][nt], 0, 0, 0);
                acc[mt][nt] = __builtin_amdgcn_mfma_f32_16x16x32_bf16(ah[mt], bl[nt], acc[mt][nt], 0, 0, 0);
                acc[mt][nt] = __builtin_amdgcn_mfma_f32_16x16x32_bf16(al[mt], bh[nt], acc[mt][nt], 0, 0, 0);
            }
        // aT2 region disjoint from h2bf -> no internal barrier
        float* A = &lds[it * IT + ATO];
#pragma unroll
        for (int mt = 0; mt < 2; ++mt)
#pragma unroll
            for (int nt = 0; nt < 2; ++nt)
#pragma unroll
                for (int r = 0; r < 4; ++r) {
                    int m = mt * 16 + q * 4 + r;
                    int n = nt * 16 + m16;
                    float s = acc[mt][nt][r];
                    s = (s > 0.f) ? s : ALPHA * s;
                    A[(half * 32 + m) * 33 + n] = s;
                }
    }
    __syncthreads();

    // ---- phase 8: softmax ----
    {
        int row = tid >> 1, q = tid & 1;
        int it = row >> 6, rm = row & 63;
        float* rp = &lds[it * IT + ATO + rm * 33];
        float ev[16];
        float mx = -INFINITY;
#pragma unroll
        for (int k = 0; k < 16; ++k) { ev[k] = rp[q + 2 * k]; mx = fmaxf(mx, ev[k]); }
        mx = fmaxf(mx, __shfl_xor(mx, 1));
        float s = 0.f;
#pragma unroll
        for (int k = 0; k < 16; ++k) { ev[k] = __expf(ev[k] - mx); s += ev[k]; }
        s += __shfl_xor(s, 1);
        float inv = 1.f / s;
#pragma unroll
        for (int k = 0; k < 16; ++k) rp[q + 2 * k] = ev[k] * inv;
    }
    __syncthreads();

    // ---- phase 9+10: (att2 @ h2) via MFMA, D[pos][n] -> bn2 -> pool -> relu -> p2f
    {
        const int wave = tid >> 6, lane = tid & 63;
        const int it = wave >> 1, half = wave & 1;
        const int m16 = lane & 15, q = lane >> 4;
        const unsigned short* U = (const unsigned short*)(lds + it * IT);
        const float* AT = &lds[it * IT + ATO];

        // A-frag: A[pos=m16][k=m] = h2[ch][pos]; h2bf hi ushort base 1716, lo 2508
        int kd = m16 >> 1, par = m16 & 1;
        union { unsigned u[4]; short8 v; } HA, LA;
#pragma unroll
        for (int i = 0; i < 4; ++i) {
            int ch = half * 32 + q * 8 + 2 * i;
            unsigned h0 = U[1716 + kd * 132 + ch * 2 + par];
            unsigned h1u = U[1716 + kd * 132 + (ch + 1) * 2 + par];
            unsigned l0 = U[2508 + kd * 132 + ch * 2 + par];
            unsigned l1 = U[2508 + kd * 132 + (ch + 1) * 2 + par];
            HA.u[i] = h0 | (h1u << 16);
            LA.u[i] = l0 | (l1 << 16);
        }
        // B-frags: att2 rows -> bf16 hi/lo via cvt_pk
        short8 bh[2], bl[2];
#pragma unroll
        for (int nt = 0; nt < 2; ++nt) {
            union { unsigned u[4]; short8 v; } H, L;
#pragma unroll
            for (int i = 0; i < 4; ++i) {
                int m = q * 8 + 2 * i;
                float a0 = AT[(half * 32 + m) * 33 + nt * 16 + m16];
                float a1 = AT[(half * 32 + m + 1) * 33 + nt * 16 + m16];
                unsigned hp, lp;
                hilo_pair(a0, a1, hp, lp);
                H.u[i] = hp; L.u[i] = lp;
            }
            bh[nt] = H.v; bl[nt] = L.v;
        }
        v4f zz = {0.f, 0.f, 0.f, 0.f};
        v4f acc[2]; acc[0] = zz; acc[1] = zz;
#pragma unroll
        for (int nt = 0; nt < 2; ++nt) {
            acc[nt] = __builtin_amdgcn_mfma_f32_16x16x32_bf16(HA.v, bh[nt], acc[nt], 0, 0, 0);
            acc[nt] = __builtin_amdgcn_mfma_f32_16x16x32_bf16(HA.v, bl[nt], acc[nt], 0, 0, 0);
            acc[nt] = __builtin_amdgcn_mfma_f32_16x16x32_bf16(LA.v, bh[nt], acc[nt], 0, 0, 0);
        }
        // epilogue: D[pos=q*4+r][n]; p2f f32 at [0,384) (pt dead) -> no barrier
        if (q < 3) {
#pragma unroll
            for (int nt = 0; nt < 2; ++nt) {
                int n = nt * 16 + m16;
                float inv = cst[64 + n], sh = cst[96 + n];
#pragma unroll
                for (int rr = 0; rr < 2; ++rr) {
                    int j = q * 2 + rr;
                    float v0 = acc[nt][rr * 2] * inv + sh;
                    float v1 = acc[nt][rr * 2 + 1] * inv + sh;
                    lds[it * IT + n * 12 + half * 6 + j] =
                        fmaxf(fmaxf(v0, v1), 0.f);
                }
            }
        }
    }
    __syncthreads();

    // ---- phase 11: linear 384 -> 13, both items; float4 dot ----
    if (tid < 208) {
        int s8 = tid & 7;
        int rest = tid >> 3;
        int it = (rest >= 13) ? 1 : 0;
        int o = rest - it * 13;
        const float4* wv4 = (const float4*)(lw + o * 384 + s8 * 48);
        const float4* fv4 = (const float4*)&lds[it * IT + s8 * 48];
        float s = 0.f;
#pragma unroll
        for (int i = 0; i < 12; ++i) {
            float4 w4 = wv4[i];
            float4 f4 = fv4[i];
            s += f4.x * w4.x + f4.y * w4.y + f4.z * w4.z + f4.w * w4.w;
        }
        s += __shfl_down(s, 4, 8);
        s += __shfl_down(s, 2, 8);
        s += __shfl_down(s, 1, 8);
        if (s8 == 0) out[(size_t)(b0 + it) * 13 + o] = s + lb[o];
    }
}

extern "C" void kernel_launch(void* const* d_in, const int* in_sizes, int n_in,
                              void* d_out, int out_size, void* d_ws, size_t ws_size,
                              hipStream_t stream) {
    const float* x   = (const float*)d_in[0];
    const float* w1  = (const float*)d_in[1];
    const float* b1  = (const float*)d_in[2];
    const float* g1  = (const float*)d_in[3];
    const float* be1 = (const float*)d_in[4];
    const float* mu1 = (const float*)d_in[5];
    const float* va1 = (const float*)d_in[6];
    const float* w2  = (const float*)d_in[7];
    const float* b2  = (const float*)d_in[8];
    const float* g2  = (const float*)d_in[9];
    const float* be2 = (const float*)d_in[10];
    const float* mu2 = (const float*)d_in[11];
    const float* va2 = (const float*)d_in[12];
    const float* lw  = (const float*)d_in[13];
    const float* lb  = (const float*)d_in[14];
    float* out = (float*)d_out;
    unsigned short* ws16 = (unsigned short*)d_ws;

    // pack conv1 + conv2 weights into MFMA B-fragments (hi/lo bf16), 73.7 KB in d_ws
    prep_kernel<<<9, 256, 0, stream>>>(w1, w2, ws16);

    int B = in_sizes[0] / 1250;  // 16384
    gcn_kernel<<<B / 2, 256, 0, stream>>>(x, w1, b1, g1, be1, mu1, va1,
                                          w2, b2, g2, be2, mu2, va2, lw, lb,
                                          ws16, out);
}

// Round 6
// 271.911 us; speedup vs baseline: 1.7371x; 1.0676x over previous
//
#include <hip/hip_runtime.h>
#include <math.h>

#define ALPHA 0.2f
#define BN_EPS 1e-5f

typedef __attribute__((ext_vector_type(8))) short short8;
typedef __attribute__((ext_vector_type(4))) float v4f;

// ---- bf16 bit helpers (RNE) ----
__device__ __forceinline__ unsigned short f2bf_rne(float f) {
    union { float f; unsigned u; } x; x.f = f;
    unsigned r = x.u + 0x7FFFu + ((x.u >> 16) & 1u);
    return (unsigned short)(r >> 16);
}
__device__ __forceinline__ float bf2f(unsigned short h) {
    union { float f; unsigned u; } x; x.u = ((unsigned)h) << 16;
    return x.f;
}
// packed f32x2 -> bf16x2 (a0 -> low16). Rounding mode of HW cvt_pk is
// irrelevant for hi/lo pairs: lo is computed against the actual hi.
__device__ __forceinline__ unsigned cvtpk_bf16(float a0, float a1) {
    unsigned r;
    asm("v_cvt_pk_bf16_f32 %0, %1, %2" : "=v"(r) : "v"(a0), "v"(a1));
    return r;
}
__device__ __forceinline__ void hilo_pair(float a0, float a1, unsigned& hp, unsigned& lp) {
    hp = cvtpk_bf16(a0, a1);
    union { unsigned u; float f; } c0, c1;
    c0.u = hp << 16; c1.u = hp & 0xFFFF0000u;
    lp = cvtpk_bf16(a0 - c0.f, a1 - c1.f);
}
// ((hi:lo) >> sh) & 0xffffffff, sh in {0,16}
__device__ __forceinline__ unsigned funnel16(unsigned hi, unsigned lo, int sh) {
    return (unsigned)((((unsigned long long)hi << 32) | lo) >> sh);
}

// ======== prep kernel: pack conv1 + conv2 weights as MFMA B-fragments ========
// conv1: K-order k' = ickh*16 + kw (kw 0..15, pad>=11 zero; ickh 0..25, pad 25 zero).
//   Kt = k'/32 in [0,13). Slot s = (Nt*13+Kt)*64+lane holds 8 ushorts:
//   elem j <-> B[k'=Kt*32+(lane>>4)*8+j][oc=Nt*16+(lane&15)].
//   hi at ws16[0..13312), lo at ws16[13312..26624).
// conv2 (kw-split, 5 GEMMs of K=32=ic): slot s2 = ((kw*2+nt)*64+lane):
//   elem j <-> B_kw[ic=(lane>>4)*8+j][oc=nt*16+(lane&15)] = w2[oc][ic][kw].
//   hi at ws16[26624..31744), lo at ws16[31744..36864).
__global__ __launch_bounds__(256) void prep_kernel(const float* __restrict__ w1,
                                                   const float* __restrict__ w2,
                                                   unsigned short* __restrict__ ws16) {
    int s = blockIdx.x * 256 + threadIdx.x;
    if (s < 1664) {
        int lane = s & 63;
        int ktnt = s >> 6;           // 0..25
        int Kt = ktnt % 13;
        int Nt = ktnt / 13;
        int oc = Nt * 16 + (lane & 15);
        int quad = lane >> 4;
        for (int j = 0; j < 8; ++j) {
            int kp = Kt * 32 + quad * 8 + j;
            int kw = kp & 15, ickh = kp >> 4;
            float w = 0.f;
            if (kw < 11 && ickh < 25) w = w1[oc * 275 + ickh * 11 + kw];
            unsigned short h = f2bf_rne(w);
            ws16[s * 8 + j] = h;
            ws16[13312 + s * 8 + j] = f2bf_rne(w - bf2f(h));
        }
    } else if (s < 2304) {
        int s2 = s - 1664;
        int lane = s2 & 63;
        int ktnt = s2 >> 6;          // 0..9 = kw*2+nt
        int kw = ktnt >> 1;
        int nt = ktnt & 1;
        int oc = nt * 16 + (lane & 15);
        int quad = lane >> 4;
        for (int j = 0; j < 8; ++j) {
            int ic = quad * 8 + j;
            float w = w2[oc * 160 + ic * 5 + kw];
            unsigned short h = f2bf_rne(w);
            ws16[26624 + s2 * 8 + j] = h;
            ws16[31744 + s2 * 8 + j] = f2bf_rne(w - bf2f(h));
        }
    }
}

// ======== main kernel ========
// Per-item LDS map (dwords, stride IT=2984), regions overlap by lifetime:
//  [0,858)    : hbf-HI (dw kd*66+ch, kd=pos>>1 0..12)  ph1epi..ph4+5-reads;
//               pt [0,832)  ph4+5epi..ph6-reads (barrier inside ph4+5);
//               h2bf hi [0,396)+lo [396,792)  ph6epi..ph9+10-reads (barrier in ph6);
//               p2f f32 [0,384)  ph9+10epi..ph11 (barrier inside ph9+10)
//  [858,1716) : hbf-LO  ph1epi..ph2-reads only (barrier inside ph2)
//  [858,2970) : aT f32 [64][33]  ph2epi..ph4+5-reads;
//               aT2  ph7epi..ph9+10-reads (ph7 reads h2bf at [0,792) - disjoint)
//  [1716,2787): xb bf16 halo'd input, 51 rows x 21dw (row 50 zeroed)  ph0..ph1
//               (aT overlays from ph2epi on - xb dead by then)
// cst @5968 [4][32]. Total 6096 dw = 24384 B -> 6 blocks/CU.
#define IT 2984
#define HLO 858
#define XB 1716
#define CSTO 5968
#define LDS_TOTAL (5968 + 128)

__global__ __launch_bounds__(256, 6) void gcn_kernel(
    const float* __restrict__ x,
    const float* __restrict__ w1, const float* __restrict__ b1,
    const float* __restrict__ g1, const float* __restrict__ be1,
    const float* __restrict__ mu1, const float* __restrict__ va1,
    const float* __restrict__ w2, const float* __restrict__ b2,
    const float* __restrict__ g2, const float* __restrict__ be2,
    const float* __restrict__ mu2, const float* __restrict__ va2,
    const float* __restrict__ lw, const float* __restrict__ lb,
    const unsigned short* __restrict__ ws16,
    float* __restrict__ out)
{
    __shared__ float lds[LDS_TOTAL];
    float* cst = lds + CSTO;

    const int tid = threadIdx.x;
    const int b0  = blockIdx.x * 2;

    // ---- phase 0: load 2 items as float2 -> bf16 halo'd xb rows; BN consts ----
    // halo index hx in [0,40): value = x[w=(hx-5) mod 25]; main hx=5+w,
    // left halo hx=w-20 (w>=20), right halo hx=30+w (w<=9). Row stride 42 us.
    {
        const float2* xg2 = (const float2*)(x + (size_t)b0 * 1250);
        for (int i2 = tid; i2 < 1250; i2 += 256) {
            float2 v = xg2[i2];
            int i = 2 * i2;
            int it = (i >= 1250) ? 1 : 0;
            int j = i - it * 1250;
            unsigned short* XU = (unsigned short*)(lds + it * IT + XB);
            {
                int c = j / 250; int r = j - c * 250;
                int h = r / 50;  int w50 = r - h * 50;
                int ha = (w50 >= 25) ? 1 : 0;
                int w = w50 - ha * 25;
                int base = (ha * 25 + c * 5 + h) * 42;
                unsigned short u = f2bf_rne(v.x);
                XU[base + 5 + w] = u;
                if (w >= 20) XU[base + w - 20] = u;
                if (w <= 9)  XU[base + 30 + w] = u;
            }
            {
                int j1 = j + 1;
                int c = j1 / 250; int r = j1 - c * 250;
                int h = r / 50;  int w51 = r - h * 50;
                int hb = (w51 >= 25) ? 1 : 0;
                int w = w51 - hb * 25;
                int base = (hb * 25 + c * 5 + h) * 42;
                unsigned short u = f2bf_rne(v.y);
                XU[base + 5 + w] = u;
                if (w >= 20) XU[base + w - 20] = u;
                if (w <= 9)  XU[base + 30 + w] = u;
            }
        }
        // zero pad row 50 (read when ickh==25; B=0 there but NaN*0=NaN)
        if (tid < 42) {
            int itz = (tid >= 21) ? 1 : 0;
            lds[itz * IT + XB + 1050 + (tid - itz * 21)] = 0.f;
        }
    }
    if (tid < 64) {
        int oc = tid & 31;
        if (tid < 32) {
            float inv = g1[oc] * rsqrtf(va1[oc] + BN_EPS);
            cst[oc]      = inv;
            cst[32 + oc] = be1[oc] - mu1[oc] * inv;
        } else {
            float inv = g2[oc] * rsqrtf(va2[oc] + BN_EPS);
            cst[64 + oc] = inv;
            cst[96 + oc] = be2[oc] - mu2[oc] * inv;
        }
    }
    __syncthreads();

    // ---- phase 1: conv1 via MFMA 16x16x32 bf16 (A direct from xb, B=hi+lo) ----
    // M remap: mg = half*32 + pos (junk rows pos>=25 computed, discarded in epi).
    {
        const int wave = tid >> 6, lane = tid & 63;
        const int it = wave >> 1;
        const int Mtb = (wave & 1) * 2;
        const int quad = lane >> 4, m16 = lane & 15;
        const int kw0 = (quad & 1) * 8;
        const int ickh0 = quad >> 1;
        const unsigned* XD = (const unsigned*)(lds + it * IT + XB);

        int ub[2], sh[2];
#pragma unroll
        for (int mt = 0; mt < 2; ++mt) {
            int mg = (Mtb + mt) * 16 + m16;
            int half = mg >> 5, pos = mg & 31;
            int ux = (half * 25 + ickh0) * 42 + pos + kw0;
            ub[mt] = ux >> 1;
            sh[mt] = (ux & 1) << 4;
        }

        v4f zz = {0.f, 0.f, 0.f, 0.f};
        v4f acc[2][2];
        acc[0][0] = zz; acc[0][1] = zz; acc[1][0] = zz; acc[1][1] = zz;

        for (int Kt = 0; Kt < 13; ++Kt) {
            union { unsigned u[4]; short8 v; } af[2];
#pragma unroll
            for (int mt = 0; mt < 2; ++mt) {
                int b = ub[mt] + Kt * 42;      // ickh advances 2 rows per Kt
                unsigned d0 = XD[b + 0], d1 = XD[b + 1], d2 = XD[b + 2];
                unsigned d3 = XD[b + 3], d4 = XD[b + 4];
                af[mt].u[0] = funnel16(d1, d0, sh[mt]);
                af[mt].u[1] = funnel16(d2, d1, sh[mt]);
                af[mt].u[2] = funnel16(d3, d2, sh[mt]);
                af[mt].u[3] = funnel16(d4, d3, sh[mt]);
            }
#pragma unroll
            for (int nt = 0; nt < 2; ++nt) {
                const short8* ph = (const short8*)(ws16 + ((nt * 13 + Kt) * 64 + lane) * 8);
                const short8* pl = (const short8*)(ws16 + 13312 + ((nt * 13 + Kt) * 64 + lane) * 8);
                short8 bh = *ph;
                short8 bl = *pl;
#pragma unroll
                for (int mt = 0; mt < 2; ++mt) {
                    acc[mt][nt] = __builtin_amdgcn_mfma_f32_16x16x32_bf16(af[mt].v, bh, acc[mt][nt], 0, 0, 0);
                    acc[mt][nt] = __builtin_amdgcn_mfma_f32_16x16x32_bf16(af[mt].v, bl, acc[mt][nt], 0, 0, 0);
                }
            }
        }

        // epilogue: D rows quad*4+r are mg; in-lane r-pairs = pos-pairs -> one
        // hilo dword per (kd,ch). hi dw kd*66+ch, lo +858. Pair (24,25): odd
        // slot holds junk (finite acc), masked by ph2 / discarded by ph4+5.
        // xb [1716+) and hbf [0,1716) disjoint -> no internal barrier.
        float biasv0 = b1[m16], biasv1 = b1[16 + m16];
        unsigned* HD = (unsigned*)(lds + it * IT);
#pragma unroll
        for (int mt = 0; mt < 2; ++mt) {
#pragma unroll
            for (int rr = 0; rr < 2; ++rr) {
                int mg0 = (Mtb + mt) * 16 + quad * 4 + rr * 2;
                int half = mg0 >> 5, pos0 = mg0 & 31;
                if (pos0 <= 24) {
                    int kd = pos0 >> 1;
#pragma unroll
                    for (int nt = 0; nt < 2; ++nt) {
                        float bias = nt ? biasv1 : biasv0;
                        float v0 = acc[mt][nt][rr * 2] + bias;
                        float v1 = acc[mt][nt][rr * 2 + 1] + bias;
                        unsigned hp, lp;
                        hilo_pair(v0, v1, hp, lp);
                        int ch = half * 32 + nt * 16 + m16;
                        HD[kd * 66 + ch] = hp;
                        HD[858 + kd * 66 + ch] = lp;
                    }
                }
            }
        }
    }
    __syncthreads();

    // ---- phase 2: layer-1 scores via MFMA Gram: S[m][n]=<H[m],H[n]> (K=25 pad 32)
    // reads hi+lo; internal barrier before aT epi (aT overlays hbf-lo).
    {
        const int wave = tid >> 6, lane = tid & 63;
        const int it = wave >> 1, half = wave & 1;
        const int m16 = lane & 15, q = lane >> 4;
        const unsigned* D = (const unsigned*)(lds + it * IT);
        short8 fh[2], fl[2];
#pragma unroll
        for (int t = 0; t < 2; ++t) {
            int row = half * 32 + t * 16 + m16;
            union { unsigned u[4]; short8 v; } H, L;
#pragma unroll
            for (int i = 0; i < 4; ++i) {
                int k0 = q * 8 + 2 * i;
                unsigned mh = D[(k0 >> 1) * 66 + row];
                unsigned ml = D[858 + (k0 >> 1) * 66 + row];
                if (k0 == 24) { mh &= 0xFFFFu; ml &= 0xFFFFu; }
                if (k0 > 24)  { mh = 0u; ml = 0u; }
                H.u[i] = mh; L.u[i] = ml;
            }
            fh[t] = H.v; fl[t] = L.v;
        }
        v4f zz = {0.f, 0.f, 0.f, 0.f};
        v4f acc[2][2];
        acc[0][0] = zz; acc[0][1] = zz; acc[1][0] = zz; acc[1][1] = zz;
#pragma unroll
        for (int mt = 0; mt < 2; ++mt)
#pragma unroll
            for (int nt = 0; nt < 2; ++nt) {
                acc[mt][nt] = __builtin_amdgcn_mfma_f32_16x16x32_bf16(fh[mt], fh[nt], acc[mt][nt], 0, 0, 0);
                acc[mt][nt] = __builtin_amdgcn_mfma_f32_16x16x32_bf16(fh[mt], fl[nt], acc[mt][nt], 0, 0, 0);
                acc[mt][nt] = __builtin_amdgcn_mfma_f32_16x16x32_bf16(fl[mt], fh[nt], acc[mt][nt], 0, 0, 0);
            }
        __syncthreads();   // all hbf-lo reads done before aT overwrites [858,2970)
        float* A = &lds[it * IT + HLO];
#pragma unroll
        for (int mt = 0; mt < 2; ++mt)
#pragma unroll
            for (int nt = 0; nt < 2; ++nt)
#pragma unroll
                for (int r = 0; r < 4; ++r) {
                    int m = mt * 16 + q * 4 + r;
                    int n = nt * 16 + m16;
                    float s = acc[mt][nt][r];
                    s = (s > 0.f) ? s : ALPHA * s;
                    A[(half * 32 + m) * 33 + n] = s;
                }
    }
    __syncthreads();

    // ---- phase 3: softmax over n; 128 rows x 2 lanes ----
    {
        int row = tid >> 1, q = tid & 1;
        int it = row >> 6, rm = row & 63;
        float* rp = &lds[it * IT + HLO + rm * 33];
        float ev[16];
        float mx = -INFINITY;
#pragma unroll
        for (int k = 0; k < 16; ++k) { ev[k] = rp[q + 2 * k]; mx = fmaxf(mx, ev[k]); }
        mx = fmaxf(mx, __shfl_xor(mx, 1));
        float s = 0.f;
#pragma unroll
        for (int k = 0; k < 16; ++k) { ev[k] = __expf(ev[k] - mx); s += ev[k]; }
        s += __shfl_xor(s, 1);
        float inv = 1.f / s;
#pragma unroll
        for (int k = 0; k < 16; ++k) rp[q + 2 * k] = ev[k] * inv;
    }
    __syncthreads();

    // ---- phase 4+5: (att @ h1) via MFMA, D[pos][n] -> bn1 -> pool (in-lane)
    //      -> relu -> pt. A = h1 HI ONLY (lo term dropped: |err| <= 2^-9*max|h1|,
    //      att convex). B = att hi+lo. 2-term: AhBh + AhBl.
    {
        const int wave = tid >> 6, lane = tid & 63;
        const int it = wave >> 1, half = wave & 1;
        const int m16 = lane & 15, q = lane >> 4;
        const unsigned short* U = (const unsigned short*)(lds + it * IT);
        const float* AT = &lds[it * IT + HLO];

        // A-frags (hi): A[pos][k=m] = h1[ch=half*32+m][pos]; pos = mt*16 + m16
        short8 ah[2];
#pragma unroll
        for (int mt = 0; mt < 2; ++mt) {
            int pos = mt * 16 + m16;
            int kd = pos >> 1, par = pos & 1;
            union { unsigned u[4]; short8 v; } H;
#pragma unroll
            for (int i = 0; i < 4; ++i) {
                int ch = half * 32 + q * 8 + 2 * i;
                unsigned h0 = U[kd * 132 + ch * 2 + par];
                unsigned h1u = U[kd * 132 + (ch + 1) * 2 + par];
                H.u[i] = h0 | (h1u << 16);
            }
            ah[mt] = H.v;
        }
        // B-frags: B[k=m][n] = att from aT (f32 -> bf16 hi/lo via cvt_pk)
        short8 bh[2], bl[2];
#pragma unroll
        for (int nt = 0; nt < 2; ++nt) {
            union { unsigned u[4]; short8 v; } H, L;
#pragma unroll
            for (int i = 0; i < 4; ++i) {
                int m = q * 8 + 2 * i;
                float a0 = AT[(half * 32 + m) * 33 + nt * 16 + m16];
                float a1 = AT[(half * 32 + m + 1) * 33 + nt * 16 + m16];
                unsigned hp, lp;
                hilo_pair(a0, a1, hp, lp);
                H.u[i] = hp; L.u[i] = lp;
            }
            bh[nt] = H.v; bl[nt] = L.v;
        }
        v4f zz = {0.f, 0.f, 0.f, 0.f};
        v4f acc[2][2];
        acc[0][0] = zz; acc[0][1] = zz; acc[1][0] = zz; acc[1][1] = zz;
#pragma unroll
        for (int mt = 0; mt < 2; ++mt)
#pragma unroll
            for (int nt = 0; nt < 2; ++nt) {
                acc[mt][nt] = __builtin_amdgcn_mfma_f32_16x16x32_bf16(ah[mt], bh[nt], acc[mt][nt], 0, 0, 0);
                acc[mt][nt] = __builtin_amdgcn_mfma_f32_16x16x32_bf16(ah[mt], bl[nt], acc[mt][nt], 0, 0, 0);
            }

        __syncthreads();   // all hbf-hi reads done before pt overwrites [0,832)

        // epilogue: pos = mt*16 + q*4 + r (r-pairs pool in-lane); n = nt*16+m16
        unsigned short* PT = (unsigned short*)(lds + it * IT) + half * 832;
#pragma unroll
        for (int mt = 0; mt < 2; ++mt)
#pragma unroll
            for (int nt = 0; nt < 2; ++nt) {
                int n = nt * 16 + m16;
                float inv = cst[n], sh = cst[32 + n];
#pragma unroll
                for (int rr = 0; rr < 2; ++rr) {
                    int pos0 = mt * 16 + q * 4 + rr * 2;
                    if (pos0 < 24) {
                        float v0 = acc[mt][nt][rr * 2] * inv + sh;
                        float v1 = acc[mt][nt][rr * 2 + 1] * inv + sh;
                        float p = fmaxf(fmaxf(v0, v1), 0.f);
                        int j = pos0 >> 1;
                        unsigned short h = f2bf_rne(p);
                        PT[(n >> 1) * 26 + j * 2 + (n & 1)] = h;
                        PT[416 + (n >> 1) * 26 + j * 2 + (n & 1)] = f2bf_rne(p - bf2f(h));
                    }
                }
            }
    }
    __syncthreads();

    // ---- phase 6: conv2 as 5 kw-split MFMA GEMMs (K=32=ic), A from pt ----
    {
        const int wave = tid >> 6, lane = tid & 63;
        const int it = wave >> 1, half = wave & 1;
        const int m16 = lane & 15, q = lane >> 4;
        const unsigned* PTD = (const unsigned*)(lds + it * IT) + half * 416;

        v4f zz = {0.f, 0.f, 0.f, 0.f};
        v4f acc[2]; acc[0] = zz; acc[1] = zz;
#pragma unroll
        for (int kw = 0; kw < 5; ++kw) {
            int owr = m16 + kw - 2;
            if (owr < 0) owr += 12;
            if (owr >= 12) owr -= 12;
            union { unsigned u[4]; short8 v; } H, L;
#pragma unroll
            for (int i = 0; i < 4; ++i) {
                H.u[i] = PTD[(q * 4 + i) * 13 + owr];
                L.u[i] = PTD[208 + (q * 4 + i) * 13 + owr];
            }
#pragma unroll
            for (int nt = 0; nt < 2; ++nt) {
                const short8* ph = (const short8*)(ws16 + 26624 + ((kw * 2 + nt) * 64 + lane) * 8);
                const short8* pl = (const short8*)(ws16 + 31744 + ((kw * 2 + nt) * 64 + lane) * 8);
                short8 wbh = *ph, wbl = *pl;
                acc[nt] = __builtin_amdgcn_mfma_f32_16x16x32_bf16(H.v, wbh, acc[nt], 0, 0, 0);
                acc[nt] = __builtin_amdgcn_mfma_f32_16x16x32_bf16(H.v, wbl, acc[nt], 0, 0, 0);
                acc[nt] = __builtin_amdgcn_mfma_f32_16x16x32_bf16(L.v, wbh, acc[nt], 0, 0, 0);
            }
        }

        __syncthreads();   // all pt reads done before h2bf overwrites [0,792)

        // epilogue: D[ow=q*4+r][oc]; h2bf hi dw kd*66+ch, lo +396 (kd = ow pair)
        if (q < 3) {
            unsigned* H2 = (unsigned*)(lds + it * IT);
#pragma unroll
            for (int nt = 0; nt < 2; ++nt) {
                float bias = b2[nt * 16 + m16];
                int ch = half * 32 + nt * 16 + m16;
#pragma unroll
                for (int rr = 0; rr < 2; ++rr) {
                    float v0 = acc[nt][rr * 2] + bias;
                    float v1 = acc[nt][rr * 2 + 1] + bias;
                    unsigned hp, lp;
                    hilo_pair(v0, v1, hp, lp);
                    H2[(q * 2 + rr) * 66 + ch] = hp;
                    H2[396 + (q * 2 + rr) * 66 + ch] = lp;
                }
            }
        }
    }
    __syncthreads();

    // ---- phase 7: layer-2 scores via MFMA: S[m][n]=<H2[1-half][m],H2[half][n]>, K=12 pad 32
    // reads h2bf [0,792), writes aT2 [858,2970) - disjoint, no internal barrier.
    {
        const int wave = tid >> 6, lane = tid & 63;
        const int it = wave >> 1, half = wave & 1;
        const int m16 = lane & 15, q = lane >> 4;
        const unsigned* D = (const unsigned*)(lds + it * IT);
        short8 ah[2], al[2], bh[2], bl[2];
#pragma unroll
        for (int t = 0; t < 2; ++t) {
            int rowA = (1 - half) * 32 + t * 16 + m16;
            int rowB = half * 32 + t * 16 + m16;
            union { unsigned u[4]; short8 v; } HA, LA, HB, LB;
#pragma unroll
            for (int i = 0; i < 4; ++i) {
                int k0 = q * 8 + 2 * i;
                unsigned a_h = D[(k0 >> 1) * 66 + rowA];
                unsigned a_l = D[396 + (k0 >> 1) * 66 + rowA];
                unsigned b_h = D[(k0 >> 1) * 66 + rowB];
                unsigned b_l = D[396 + (k0 >> 1) * 66 + rowB];
                if (k0 > 10) { a_h = 0u; a_l = 0u; b_h = 0u; b_l = 0u; }
                HA.u[i] = a_h; LA.u[i] = a_l; HB.u[i] = b_h; LB.u[i] = b_l;
            }
            ah[t] = HA.v; al[t] = LA.v; bh[t] = HB.v; bl[t] = LB.v;
        }
        v4f zz = {0.f, 0.f, 0.f, 0.f};
        v4f acc[2][2];
        acc[0][0] = zz; acc[0][1] = zz; acc[1][0] = zz; acc[1][1] = zz;
#pragma unroll
        for (int mt = 0; mt < 2; ++mt)
#pragma unroll
            for (int nt = 0; nt < 2; ++nt) {
                acc[mt][nt] = __builtin_amdgcn_mfma_f32_16x16x32_bf16(ah[mt], bh[nt], acc[mt][nt], 0, 0, 0);
                acc[mt][nt] = __builtin_amdgcn_mfma_f32_16x16x32_bf16(ah[mt], bl[nt], acc[mt][nt], 0, 0, 0);
                acc[mt][nt] = __builtin_amdgcn_mfma_f32_16x16x32_bf16(al[mt], bh[nt], acc[mt][nt], 0, 0, 0);
            }
        float* A = &lds[it * IT + HLO];
#pragma unroll
        for (int mt = 0; mt < 2; ++mt)
#pragma unroll
            for (int nt = 0; nt < 2; ++nt)
#pragma unroll
                for (int r = 0; r < 4; ++r) {
                    int m = mt * 16 + q * 4 + r;
                    int n = nt * 16 + m16;
                    float s = acc[mt][nt][r];
                    s = (s > 0.f) ? s : ALPHA * s;
                    A[(half * 32 + m) * 33 + n] = s;
                }
    }
    __syncthreads();

    // ---- phase 8: softmax ----
    {
        int row = tid >> 1, q = tid & 1;
        int it = row >> 6, rm = row & 63;
        float* rp = &lds[it * IT + HLO + rm * 33];
        float ev[16];
        float mx = -INFINITY;
#pragma unroll
        for (int k = 0; k < 16; ++k) { ev[k] = rp[q + 2 * k]; mx = fmaxf(mx, ev[k]); }
        mx = fmaxf(mx, __shfl_xor(mx, 1));
        float s = 0.f;
#pragma unroll
        for (int k = 0; k < 16; ++k) { ev[k] = __expf(ev[k] - mx); s += ev[k]; }
        s += __shfl_xor(s, 1);
        float inv = 1.f / s;
#pragma unroll
        for (int k = 0; k < 16; ++k) rp[q + 2 * k] = ev[k] * inv;
    }
    __syncthreads();

    // ---- phase 9+10: (att2 @ h2) via MFMA, D[pos][n] -> bn2 -> pool -> relu -> p2f
    {
        const int wave = tid >> 6, lane = tid & 63;
        const int it = wave >> 1, half = wave & 1;
        const int m16 = lane & 15, q = lane >> 4;
        const unsigned short* U = (const unsigned short*)(lds + it * IT);
        const float* AT = &lds[it * IT + HLO];

        // A-frag: A[pos=m16][k=m] = h2[ch][pos]; h2bf hi us base 0, lo us base 792
        int kd = m16 >> 1, par = m16 & 1;
        union { unsigned u[4]; short8 v; } HA, LA;
#pragma unroll
        for (int i = 0; i < 4; ++i) {
            int ch = half * 32 + q * 8 + 2 * i;
            unsigned h0 = U[kd * 132 + ch * 2 + par];
            unsigned h1u = U[kd * 132 + (ch + 1) * 2 + par];
            unsigned l0 = U[792 + kd * 132 + ch * 2 + par];
            unsigned l1 = U[792 + kd * 132 + (ch + 1) * 2 + par];
            HA.u[i] = h0 | (h1u << 16);
            LA.u[i] = l0 | (l1 << 16);
        }
        // B-frags: att2 rows -> bf16 hi/lo via cvt_pk
        short8 bh[2], bl[2];
#pragma unroll
        for (int nt = 0; nt < 2; ++nt) {
            union { unsigned u[4]; short8 v; } H, L;
#pragma unroll
            for (int i = 0; i < 4; ++i) {
                int m = q * 8 + 2 * i;
                float a0 = AT[(half * 32 + m) * 33 + nt * 16 + m16];
                float a1 = AT[(half * 32 + m + 1) * 33 + nt * 16 + m16];
                unsigned hp, lp;
                hilo_pair(a0, a1, hp, lp);
                H.u[i] = hp; L.u[i] = lp;
            }
            bh[nt] = H.v; bl[nt] = L.v;
        }
        v4f zz = {0.f, 0.f, 0.f, 0.f};
        v4f acc[2]; acc[0] = zz; acc[1] = zz;
#pragma unroll
        for (int nt = 0; nt < 2; ++nt) {
            acc[nt] = __builtin_amdgcn_mfma_f32_16x16x32_bf16(HA.v, bh[nt], acc[nt], 0, 0, 0);
            acc[nt] = __builtin_amdgcn_mfma_f32_16x16x32_bf16(HA.v, bl[nt], acc[nt], 0, 0, 0);
            acc[nt] = __builtin_amdgcn_mfma_f32_16x16x32_bf16(LA.v, bh[nt], acc[nt], 0, 0, 0);
        }

        __syncthreads();   // all h2bf reads done before p2f overwrites [0,384)

        // epilogue: D[pos=q*4+r][n=nt*16+m16]
        if (q < 3) {
#pragma unroll
            for (int nt = 0; nt < 2; ++nt) {
                int n = nt * 16 + m16;
                float inv = cst[64 + n], sh = cst[96 + n];
#pragma unroll
                for (int rr = 0; rr < 2; ++rr) {
                    int j = q * 2 + rr;
                    float v0 = acc[nt][rr * 2] * inv + sh;
                    float v1 = acc[nt][rr * 2 + 1] * inv + sh;
                    lds[it * IT + n * 12 + half * 6 + j] =
                        fmaxf(fmaxf(v0, v1), 0.f);
                }
            }
        }
    }
    __syncthreads();

    // ---- phase 11: linear 384 -> 13, both items; float4 dot ----
    if (tid < 208) {
        int s8 = tid & 7;
        int rest = tid >> 3;
        int it = (rest >= 13) ? 1 : 0;
        int o = rest - it * 13;
        const float4* wv4 = (const float4*)(lw + o * 384 + s8 * 48);
        const float4* fv4 = (const float4*)&lds[it * IT + s8 * 48];
        float s = 0.f;
#pragma unroll
        for (int i = 0; i < 12; ++i) {
            float4 w4 = wv4[i];
            float4 f4 = fv4[i];
            s += f4.x * w4.x + f4.y * w4.y + f4.z * w4.z + f4.w * w4.w;
        }
        s += __shfl_down(s, 4, 8);
        s += __shfl_down(s, 2, 8);
        s += __shfl_down(s, 1, 8);
        if (s8 == 0) out[(size_t)(b0 + it) * 13 + o] = s + lb[o];
    }
}

extern "C" void kernel_launch(void* const* d_in, const int* in_sizes, int n_in,
                              void* d_out, int out_size, void* d_ws, size_t ws_size,
                              hipStream_t stream) {
    const float* x   = (const float*)d_in[0];
    const float* w1  = (const float*)d_in[1];
    const float* b1  = (const float*)d_in[2];
    const float* g1  = (const float*)d_in[3];
    const float* be1 = (const float*)d_in[4];
    const float* mu1 = (const float*)d_in[5];
    const float* va1 = (const float*)d_in[6];
    const float* w2  = (const float*)d_in[7];
    const float* b2  = (const float*)d_in[8];
    const float* g2  = (const float*)d_in[9];
    const float* be2 = (const float*)d_in[10];
    const float* mu2 = (const float*)d_in[11];
    const float* va2 = (const float*)d_in[12];
    const float* lw  = (const float*)d_in[13];
    const float* lb  = (const float*)d_in[14];
    float* out = (float*)d_out;
    unsigned short* ws16 = (unsigned short*)d_ws;

    // pack conv1 + conv2 weights into MFMA B-fragments (hi/lo bf16), 73.7 KB in d_ws
    prep_kernel<<<9, 256, 0, stream>>>(w1, w2, ws16);

    int B = in_sizes[0] / 1250;  // 16384
    gcn_kernel<<<B / 2, 256, 0, stream>>>(x, w1, b1, g1, be1, mu1, va1,
                                          w2, b2, g2, be2, mu2, va2, lw, lb,
                                          ws16, out);
}

// Round 7
// 245.571 us; speedup vs baseline: 1.9235x; 1.1073x over previous
//
#include <hip/hip_runtime.h>
#include <math.h>

#define ALPHA 0.2f
#define BN_EPS 1e-5f

typedef __attribute__((ext_vector_type(8))) short short8;
typedef __attribute__((ext_vector_type(4))) float v4f;

// ---- bf16 bit helpers (RNE) ----
__device__ __forceinline__ unsigned short f2bf_rne(float f) {
    union { float f; unsigned u; } x; x.f = f;
    unsigned r = x.u + 0x7FFFu + ((x.u >> 16) & 1u);
    return (unsigned short)(r >> 16);
}
__device__ __forceinline__ float bf2f(unsigned short h) {
    union { float f; unsigned u; } x; x.u = ((unsigned)h) << 16;
    return x.f;
}
// packed f32x2 -> bf16x2 (a0 -> low16). Rounding mode of HW cvt_pk is
// irrelevant for hi/lo pairs: lo is computed against the actual hi.
__device__ __forceinline__ unsigned cvtpk_bf16(float a0, float a1) {
    unsigned r;
    asm("v_cvt_pk_bf16_f32 %0, %1, %2" : "=v"(r) : "v"(a0), "v"(a1));
    return r;
}
__device__ __forceinline__ void hilo_pair(float a0, float a1, unsigned& hp, unsigned& lp) {
    hp = cvtpk_bf16(a0, a1);
    union { unsigned u; float f; } c0, c1;
    c0.u = hp << 16; c1.u = hp & 0xFFFF0000u;
    lp = cvtpk_bf16(a0 - c0.f, a1 - c1.f);
}

// ======== prep kernel: pack conv1 + conv2 weights as MFMA B-fragments ========
// conv1 (kw-split, 11 GEMMs of K=25 pad 32 over k=ic*5+kh): slot
//   s = (kw*2+nt)*64+lane, elem j <-> B_kw[k=(lane>>4)*8+j][oc=nt*16+(lane&15)]
//   = w1[oc*275 + k*11 + kw], zero for k>=25.
//   hi at ws16[0..11264), lo at ws16[11264..22528).
// conv2 (kw-split, 5 GEMMs of K=32=ic): slot s2 = ((kw*2+nt)*64+lane):
//   elem j <-> B_kw[ic=(lane>>4)*8+j][oc=nt*16+(lane&15)] = w2[oc][ic][kw].
//   hi at ws16[22528..27648), lo at ws16[27648..32768).  Total 64 KB.
__global__ __launch_bounds__(256) void prep_kernel(const float* __restrict__ w1,
                                                   const float* __restrict__ w2,
                                                   unsigned short* __restrict__ ws16) {
    int s = blockIdx.x * 256 + threadIdx.x;
    if (s < 1408) {
        int lane = s & 63;
        int ktnt = s >> 6;           // 0..21 = kw*2+nt
        int kw = ktnt >> 1;
        int nt = ktnt & 1;
        int oc = nt * 16 + (lane & 15);
        int quad = lane >> 4;
        for (int j = 0; j < 8; ++j) {
            int k = quad * 8 + j;    // ic*5+kh, pad >=25 zero
            float w = (k < 25) ? w1[oc * 275 + k * 11 + kw] : 0.f;
            unsigned short h = f2bf_rne(w);
            ws16[s * 8 + j] = h;
            ws16[11264 + s * 8 + j] = f2bf_rne(w - bf2f(h));
        }
    } else if (s < 2048) {
        int s2 = s - 1408;
        int lane = s2 & 63;
        int ktnt = s2 >> 6;          // 0..9 = kw*2+nt
        int kw = ktnt >> 1;
        int nt = ktnt & 1;
        int oc = nt * 16 + (lane & 15);
        int quad = lane >> 4;
        for (int j = 0; j < 8; ++j) {
            int ic = quad * 8 + j;
            float w = w2[oc * 160 + ic * 5 + kw];
            unsigned short h = f2bf_rne(w);
            ws16[22528 + s2 * 8 + j] = h;
            ws16[27648 + s2 * 8 + j] = f2bf_rne(w - bf2f(h));
        }
    }
}

// ======== main kernel ========
// Per-item LDS map (dwords, stride IT=2984), regions overlap by lifetime:
//  [0,858)    : hbf-HI (dw kd*66+ch, kd=pos>>1 0..12)  ph1epi..ph4+5-reads;
//               pt [0,832)  ph4+5epi..ph6-reads (barrier inside ph4+5);
//               h2bf hi [0,396)+lo [396,792)  ph6epi..ph9+10-reads (barrier in ph6);
//               p2f f32 [0,384)  ph9+10epi..ph11 (barrier inside ph9+10)
//  [858,1716) : hbf-LO  ph1epi..ph2-reads only (barrier inside ph2)
//  [858,2970) : aT f32 [64][33]  ph2epi..ph4+5-reads;
//               aT2  ph7epi..ph9+10-reads
//  [860,2260) : xkT bf16 x^T pair-packed halo'd: [half][w'=0..34][20dw rows,
//               kd=k>>1 0..12, k=25..31 zero, 16..19 slack]  ph0..ph1-MFMAs
//               (barrier inside ph1 before hbf epi overwrites [858,1716))
// cst @5968 [4][32]. Total 6096 dw = 24384 B -> 6 blocks/CU.
#define IT 2984
#define HLO 858
#define XKT 860
#define CSTO 5968
#define LDS_TOTAL (5968 + 128)

__global__ __launch_bounds__(256, 6) void gcn_kernel(
    const float* __restrict__ x,
    const float* __restrict__ w1, const float* __restrict__ b1,
    const float* __restrict__ g1, const float* __restrict__ be1,
    const float* __restrict__ mu1, const float* __restrict__ va1,
    const float* __restrict__ w2, const float* __restrict__ b2,
    const float* __restrict__ g2, const float* __restrict__ be2,
    const float* __restrict__ mu2, const float* __restrict__ va2,
    const float* __restrict__ lw, const float* __restrict__ lb,
    const unsigned short* __restrict__ ws16,
    float* __restrict__ out)
{
    __shared__ __align__(16) float lds[LDS_TOTAL];
    float* cst = lds + CSTO;

    const int tid = threadIdx.x;
    const int b0  = blockIdx.x * 2;

    // ---- phase 0: row-based load -> xkT (bf16, transposed, pair-packed, halo) ----
    // xkT row w' holds x[w=(w'-5) mod 25] at us slot k=ic*5+kh; row stride 40 us.
    // main w'=w+5; left halo w'=w-20 (w>=20); right halo w'=w+30 (w<=4).
    if (tid < 250) {
        int rowid = tid / 5;             // (it, k): 50 source rows of 50 floats
        int s = tid - rowid * 5;         // fifth-of-row: w50 in [s*10, s*10+10)
        int it = (rowid >= 25) ? 1 : 0;
        int k = rowid - it * 25;
        const float2* src = (const float2*)(x + (size_t)b0 * 1250) + it * 625 + k * 25 + s * 5;
        unsigned short* XU = (unsigned short*)(lds + it * IT + XKT);
#pragma unroll
        for (int e = 0; e < 5; ++e) {
            float2 v = src[e];
            int w50 = s * 10 + 2 * e;
            {
                int half = (w50 >= 25) ? 1 : 0;
                int w = w50 - half * 25;
                unsigned short u = f2bf_rne(v.x);
                int a = half * 1400 + (w + 5) * 40 + k;
                XU[a] = u;
                if (w >= 20) XU[a - 1000] = u;
                if (w <= 4)  XU[a + 1000] = u;
            }
            {
                int w51 = w50 + 1;
                int half = (w51 >= 25) ? 1 : 0;
                int w = w51 - half * 25;
                unsigned short u = f2bf_rne(v.y);
                int a = half * 1400 + (w + 5) * 40 + k;
                XU[a] = u;
                if (w >= 20) XU[a - 1000] = u;
                if (w <= 4)  XU[a + 1000] = u;
            }
        }
    }
    // zero pads: k=25 ushort + kd 13..15 dwords, all 140 (it,half,w') rows
    if (tid < 140) {
        int it = (tid >= 70) ? 1 : 0;
        int r2 = tid - it * 70;
        int half = (r2 >= 35) ? 1 : 0;
        int w3 = r2 - half * 35;
        int a = half * 1400 + w3 * 40;   // even
        unsigned short* XU = (unsigned short*)(lds + it * IT + XKT);
        XU[a + 25] = 0;
        unsigned* XD = (unsigned*)XU;
        XD[(a >> 1) + 13] = 0;
        XD[(a >> 1) + 14] = 0;
        XD[(a >> 1) + 15] = 0;
    }
    if (tid < 64) {
        int oc = tid & 31;
        if (tid < 32) {
            float inv = g1[oc] * rsqrtf(va1[oc] + BN_EPS);
            cst[oc]      = inv;
            cst[32 + oc] = be1[oc] - mu1[oc] * inv;
        } else {
            float inv = g2[oc] * rsqrtf(va2[oc] + BN_EPS);
            cst[64 + oc] = inv;
            cst[96 + oc] = be2[oc] - mu2[oc] * inv;
        }
    }
    __syncthreads();

    // ---- phase 1: conv1 as 11 kw-split MFMA GEMMs (K=25 pad 32), A=1 b128/tile ----
    // M remap: mg = half*32 + pos (junk rows pos>=25 clamp to 24, discarded in epi).
    {
        const int wave = tid >> 6, lane = tid & 63;
        const int it = wave >> 1;
        const int Mtb = (wave & 1) * 2;
        const int quad = lane >> 4, m16 = lane & 15;
        const unsigned* XK = (const unsigned*)(lds + it * IT + XKT);

        int ab[2];
#pragma unroll
        for (int mt = 0; mt < 2; ++mt) {
            int mg = (Mtb + mt) * 16 + m16;
            int half = mg >> 5, pos = mg & 31;
            pos = (pos > 24) ? 24 : pos;
            ab[mt] = half * 700 + pos * 20 + quad * 4;
        }

        v4f zz = {0.f, 0.f, 0.f, 0.f};
        v4f acc[2][2];
        acc[0][0] = zz; acc[0][1] = zz; acc[1][0] = zz; acc[1][1] = zz;

        for (int kw = 0; kw < 11; ++kw) {
            short8 a0 = *(const short8*)(XK + ab[0] + kw * 20);
            short8 a1 = *(const short8*)(XK + ab[1] + kw * 20);
#pragma unroll
            for (int nt = 0; nt < 2; ++nt) {
                const short8* ph = (const short8*)(ws16 + ((kw * 2 + nt) * 64 + lane) * 8);
                const short8* pl = (const short8*)(ws16 + 11264 + ((kw * 2 + nt) * 64 + lane) * 8);
                short8 bh = *ph;
                short8 bl = *pl;
                acc[0][nt] = __builtin_amdgcn_mfma_f32_16x16x32_bf16(a0, bh, acc[0][nt], 0, 0, 0);
                acc[0][nt] = __builtin_amdgcn_mfma_f32_16x16x32_bf16(a0, bl, acc[0][nt], 0, 0, 0);
                acc[1][nt] = __builtin_amdgcn_mfma_f32_16x16x32_bf16(a1, bh, acc[1][nt], 0, 0, 0);
                acc[1][nt] = __builtin_amdgcn_mfma_f32_16x16x32_bf16(a1, bl, acc[1][nt], 0, 0, 0);
            }
        }

        __syncthreads();   // all xkT reads done before hbf-lo epi overwrites [858,1716)

        // epilogue: D rows quad*4+r are mg; in-lane r-pairs = pos-pairs -> one
        // hilo dword per (kd,ch). hi dw kd*66+ch, lo +858. Pair (24,25): odd
        // slot holds junk (finite acc), masked by ph2 / discarded by ph4+5.
        float biasv0 = b1[m16], biasv1 = b1[16 + m16];
        unsigned* HD = (unsigned*)(lds + it * IT);
#pragma unroll
        for (int mt = 0; mt < 2; ++mt) {
#pragma unroll
            for (int rr = 0; rr < 2; ++rr) {
                int mg0 = (Mtb + mt) * 16 + quad * 4 + rr * 2;
                int half = mg0 >> 5, pos0 = mg0 & 31;
                if (pos0 <= 24) {
                    int kd = pos0 >> 1;
#pragma unroll
                    for (int nt = 0; nt < 2; ++nt) {
                        float bias = nt ? biasv1 : biasv0;
                        float v0 = acc[mt][nt][rr * 2] + bias;
                        float v1 = acc[mt][nt][rr * 2 + 1] + bias;
                        unsigned hp, lp;
                        hilo_pair(v0, v1, hp, lp);
                        int ch = half * 32 + nt * 16 + m16;
                        HD[kd * 66 + ch] = hp;
                        HD[858 + kd * 66 + ch] = lp;
                    }
                }
            }
        }
    }
    __syncthreads();

    // ---- phase 2: layer-1 scores via MFMA Gram: S[m][n]=<H[m],H[n]> (K=25 pad 32)
    // reads hi+lo; internal barrier before aT epi (aT overlays hbf-lo).
    {
        const int wave = tid >> 6, lane = tid & 63;
        const int it = wave >> 1, half = wave & 1;
        const int m16 = lane & 15, q = lane >> 4;
        const unsigned* D = (const unsigned*)(lds + it * IT);
        short8 fh[2], fl[2];
#pragma unroll
        for (int t = 0; t < 2; ++t) {
            int row = half * 32 + t * 16 + m16;
            union { unsigned u[4]; short8 v; } H, L;
#pragma unroll
            for (int i = 0; i < 4; ++i) {
                int k0 = q * 8 + 2 * i;
                unsigned mh = D[(k0 >> 1) * 66 + row];
                unsigned ml = D[858 + (k0 >> 1) * 66 + row];
                if (k0 == 24) { mh &= 0xFFFFu; ml &= 0xFFFFu; }
                if (k0 > 24)  { mh = 0u; ml = 0u; }
                H.u[i] = mh; L.u[i] = ml;
            }
            fh[t] = H.v; fl[t] = L.v;
        }
        v4f zz = {0.f, 0.f, 0.f, 0.f};
        v4f acc[2][2];
        acc[0][0] = zz; acc[0][1] = zz; acc[1][0] = zz; acc[1][1] = zz;
#pragma unroll
        for (int mt = 0; mt < 2; ++mt)
#pragma unroll
            for (int nt = 0; nt < 2; ++nt) {
                acc[mt][nt] = __builtin_amdgcn_mfma_f32_16x16x32_bf16(fh[mt], fh[nt], acc[mt][nt], 0, 0, 0);
                acc[mt][nt] = __builtin_amdgcn_mfma_f32_16x16x32_bf16(fh[mt], fl[nt], acc[mt][nt], 0, 0, 0);
                acc[mt][nt] = __builtin_amdgcn_mfma_f32_16x16x32_bf16(fl[mt], fh[nt], acc[mt][nt], 0, 0, 0);
            }
        __syncthreads();   // all hbf-lo reads done before aT overwrites [858,2970)
        float* A = &lds[it * IT + HLO];
#pragma unroll
        for (int mt = 0; mt < 2; ++mt)
#pragma unroll
            for (int nt = 0; nt < 2; ++nt)
#pragma unroll
                for (int r = 0; r < 4; ++r) {
                    int m = mt * 16 + q * 4 + r;
                    int n = nt * 16 + m16;
                    float s = acc[mt][nt][r];
                    s = (s > 0.f) ? s : ALPHA * s;
                    A[(half * 32 + m) * 33 + n] = s;
                }
    }
    __syncthreads();

    // ---- phase 3: softmax over n; 128 rows x 2 lanes ----
    {
        int row = tid >> 1, q = tid & 1;
        int it = row >> 6, rm = row & 63;
        float* rp = &lds[it * IT + HLO + rm * 33];
        float ev[16];
        float mx = -INFINITY;
#pragma unroll
        for (int k = 0; k < 16; ++k) { ev[k] = rp[q + 2 * k]; mx = fmaxf(mx, ev[k]); }
        mx = fmaxf(mx, __shfl_xor(mx, 1));
        float s = 0.f;
#pragma unroll
        for (int k = 0; k < 16; ++k) { ev[k] = __expf(ev[k] - mx); s += ev[k]; }
        s += __shfl_xor(s, 1);
        float inv = 1.f / s;
#pragma unroll
        for (int k = 0; k < 16; ++k) rp[q + 2 * k] = ev[k] * inv;
    }
    __syncthreads();

    // ---- phase 4+5: (att @ h1) via MFMA, D[pos][n] -> bn1 -> pool (in-lane)
    //      -> relu -> pt. A = h1 HI ONLY (lo term dropped: |err| <= 2^-9*max|h1|,
    //      att convex). B = att hi+lo. 2-term: AhBh + AhBl.
    {
        const int wave = tid >> 6, lane = tid & 63;
        const int it = wave >> 1, half = wave & 1;
        const int m16 = lane & 15, q = lane >> 4;
        const unsigned short* U = (const unsigned short*)(lds + it * IT);
        const float* AT = &lds[it * IT + HLO];

        // A-frags (hi): A[pos][k=m] = h1[ch=half*32+m][pos]; pos = mt*16 + m16
        short8 ah[2];
#pragma unroll
        for (int mt = 0; mt < 2; ++mt) {
            int pos = mt * 16 + m16;
            int kd = pos >> 1, par = pos & 1;
            union { unsigned u[4]; short8 v; } H;
#pragma unroll
            for (int i = 0; i < 4; ++i) {
                int ch = half * 32 + q * 8 + 2 * i;
                unsigned h0 = U[kd * 132 + ch * 2 + par];
                unsigned h1u = U[kd * 132 + (ch + 1) * 2 + par];
                H.u[i] = h0 | (h1u << 16);
            }
            ah[mt] = H.v;
        }
        // B-frags: B[k=m][n] = att from aT (f32 -> bf16 hi/lo via cvt_pk)
        short8 bh[2], bl[2];
#pragma unroll
        for (int nt = 0; nt < 2; ++nt) {
            union { unsigned u[4]; short8 v; } H, L;
#pragma unroll
            for (int i = 0; i < 4; ++i) {
                int m = q * 8 + 2 * i;
                float a0 = AT[(half * 32 + m) * 33 + nt * 16 + m16];
                float a1 = AT[(half * 32 + m + 1) * 33 + nt * 16 + m16];
                unsigned hp, lp;
                hilo_pair(a0, a1, hp, lp);
                H.u[i] = hp; L.u[i] = lp;
            }
            bh[nt] = H.v; bl[nt] = L.v;
        }
        v4f zz = {0.f, 0.f, 0.f, 0.f};
        v4f acc[2][2];
        acc[0][0] = zz; acc[0][1] = zz; acc[1][0] = zz; acc[1][1] = zz;
#pragma unroll
        for (int mt = 0; mt < 2; ++mt)
#pragma unroll
            for (int nt = 0; nt < 2; ++nt) {
                acc[mt][nt] = __builtin_amdgcn_mfma_f32_16x16x32_bf16(ah[mt], bh[nt], acc[mt][nt], 0, 0, 0);
                acc[mt][nt] = __builtin_amdgcn_mfma_f32_16x16x32_bf16(ah[mt], bl[nt], acc[mt][nt], 0, 0, 0);
            }

        __syncthreads();   // all hbf-hi reads done before pt overwrites [0,832)

        // epilogue: pos = mt*16 + q*4 + r (r-pairs pool in-lane); n = nt*16+m16
        unsigned short* PT = (unsigned short*)(lds + it * IT) + half * 832;
#pragma unroll
        for (int mt = 0; mt < 2; ++mt)
#pragma unroll
            for (int nt = 0; nt < 2; ++nt) {
                int n = nt * 16 + m16;
                float inv = cst[n], sh = cst[32 + n];
#pragma unroll
                for (int rr = 0; rr < 2; ++rr) {
                    int pos0 = mt * 16 + q * 4 + rr * 2;
                    if (pos0 < 24) {
                        float v0 = acc[mt][nt][rr * 2] * inv + sh;
                        float v1 = acc[mt][nt][rr * 2 + 1] * inv + sh;
                        float p = fmaxf(fmaxf(v0, v1), 0.f);
                        int j = pos0 >> 1;
                        unsigned short h = f2bf_rne(p);
                        PT[(n >> 1) * 26 + j * 2 + (n & 1)] = h;
                        PT[416 + (n >> 1) * 26 + j * 2 + (n & 1)] = f2bf_rne(p - bf2f(h));
                    }
                }
            }
    }
    __syncthreads();

    // ---- phase 6: conv2 as 5 kw-split MFMA GEMMs (K=32=ic), A from pt ----
    {
        const int wave = tid >> 6, lane = tid & 63;
        const int it = wave >> 1, half = wave & 1;
        const int m16 = lane & 15, q = lane >> 4;
        const unsigned* PTD = (const unsigned*)(lds + it * IT) + half * 416;

        v4f zz = {0.f, 0.f, 0.f, 0.f};
        v4f acc[2]; acc[0] = zz; acc[1] = zz;
#pragma unroll
        for (int kw = 0; kw < 5; ++kw) {
            int owr = m16 + kw - 2;
            if (owr < 0) owr += 12;
            if (owr >= 12) owr -= 12;
            union { unsigned u[4]; short8 v; } H, L;
#pragma unroll
            for (int i = 0; i < 4; ++i) {
                H.u[i] = PTD[(q * 4 + i) * 13 + owr];
                L.u[i] = PTD[208 + (q * 4 + i) * 13 + owr];
            }
#pragma unroll
            for (int nt = 0; nt < 2; ++nt) {
                const short8* ph = (const short8*)(ws16 + 22528 + ((kw * 2 + nt) * 64 + lane) * 8);
                const short8* pl = (const short8*)(ws16 + 27648 + ((kw * 2 + nt) * 64 + lane) * 8);
                short8 wbh = *ph, wbl = *pl;
                acc[nt] = __builtin_amdgcn_mfma_f32_16x16x32_bf16(H.v, wbh, acc[nt], 0, 0, 0);
                acc[nt] = __builtin_amdgcn_mfma_f32_16x16x32_bf16(H.v, wbl, acc[nt], 0, 0, 0);
                acc[nt] = __builtin_amdgcn_mfma_f32_16x16x32_bf16(L.v, wbh, acc[nt], 0, 0, 0);
            }
        }

        __syncthreads();   // all pt reads done before h2bf overwrites [0,792)

        // epilogue: D[ow=q*4+r][oc]; h2bf hi dw kd*66+ch, lo +396 (kd = ow pair)
        if (q < 3) {
            unsigned* H2 = (unsigned*)(lds + it * IT);
#pragma unroll
            for (int nt = 0; nt < 2; ++nt) {
                float bias = b2[nt * 16 + m16];
                int ch = half * 32 + nt * 16 + m16;
#pragma unroll
                for (int rr = 0; rr < 2; ++rr) {
                    float v0 = acc[nt][rr * 2] + bias;
                    float v1 = acc[nt][rr * 2 + 1] + bias;
                    unsigned hp, lp;
                    hilo_pair(v0, v1, hp, lp);
                    H2[(q * 2 + rr) * 66 + ch] = hp;
                    H2[396 + (q * 2 + rr) * 66 + ch] = lp;
                }
            }
        }
    }
    __syncthreads();

    // ---- phase 7: layer-2 scores via MFMA: S[m][n]=<H2[1-half][m],H2[half][n]>, K=12 pad 32
    // reads h2bf [0,792), writes aT2 [858,2970) - disjoint, no internal barrier.
    {
        const int wave = tid >> 6, lane = tid & 63;
        const int it = wave >> 1, half = wave & 1;
        const int m16 = lane & 15, q = lane >> 4;
        const unsigned* D = (const unsigned*)(lds + it * IT);
        short8 ah[2], al[2], bh[2], bl[2];
#pragma unroll
        for (int t = 0; t < 2; ++t) {
            int rowA = (1 - half) * 32 + t * 16 + m16;
            int rowB = half * 32 + t * 16 + m16;
            union { unsigned u[4]; short8 v; } HA, LA, HB, LB;
#pragma unroll
            for (int i = 0; i < 4; ++i) {
                int k0 = q * 8 + 2 * i;
                unsigned a_h = D[(k0 >> 1) * 66 + rowA];
                unsigned a_l = D[396 + (k0 >> 1) * 66 + rowA];
                unsigned b_h = D[(k0 >> 1) * 66 + rowB];
                unsigned b_l = D[396 + (k0 >> 1) * 66 + rowB];
                if (k0 > 10) { a_h = 0u; a_l = 0u; b_h = 0u; b_l = 0u; }
                HA.u[i] = a_h; LA.u[i] = a_l; HB.u[i] = b_h; LB.u[i] = b_l;
            }
            ah[t] = HA.v; al[t] = LA.v; bh[t] = HB.v; bl[t] = LB.v;
        }
        v4f zz = {0.f, 0.f, 0.f, 0.f};
        v4f acc[2][2];
        acc[0][0] = zz; acc[0][1] = zz; acc[1][0] = zz; acc[1][1] = zz;
#pragma unroll
        for (int mt = 0; mt < 2; ++mt)
#pragma unroll
            for (int nt = 0; nt < 2; ++nt) {
                acc[mt][nt] = __builtin_amdgcn_mfma_f32_16x16x32_bf16(ah[mt], bh[nt], acc[mt][nt], 0, 0, 0);
                acc[mt][nt] = __builtin_amdgcn_mfma_f32_16x16x32_bf16(ah[mt], bl[nt], acc[mt][nt], 0, 0, 0);
                acc[mt][nt] = __builtin_amdgcn_mfma_f32_16x16x32_bf16(al[mt], bh[nt], acc[mt][nt], 0, 0, 0);
            }
        float* A = &lds[it * IT + HLO];
#pragma unroll
        for (int mt = 0; mt < 2; ++mt)
#pragma unroll
            for (int nt = 0; nt < 2; ++nt)
#pragma unroll
                for (int r = 0; r < 4; ++r) {
                    int m = mt * 16 + q * 4 + r;
                    int n = nt * 16 + m16;
                    float s = acc[mt][nt][r];
                    s = (s > 0.f) ? s : ALPHA * s;
                    A[(half * 32 + m) * 33 + n] = s;
                }
    }
    __syncthreads();

    // ---- phase 8: softmax ----
    {
        int row = tid >> 1, q = tid & 1;
        int it = row >> 6, rm = row & 63;
        float* rp = &lds[it * IT + HLO + rm * 33];
        float ev[16];
        float mx = -INFINITY;
#pragma unroll
        for (int k = 0; k < 16; ++k) { ev[k] = rp[q + 2 * k]; mx = fmaxf(mx, ev[k]); }
        mx = fmaxf(mx, __shfl_xor(mx, 1));
        float s = 0.f;
#pragma unroll
        for (int k = 0; k < 16; ++k) { ev[k] = __expf(ev[k] - mx); s += ev[k]; }
        s += __shfl_xor(s, 1);
        float inv = 1.f / s;
#pragma unroll
        for (int k = 0; k < 16; ++k) rp[q + 2 * k] = ev[k] * inv;
    }
    __syncthreads();

    // ---- phase 9+10: (att2 @ h2) via MFMA, D[pos][n] -> bn2 -> pool -> relu -> p2f
    {
        const int wave = tid >> 6, lane = tid & 63;
        const int it = wave >> 1, half = wave & 1;
        const int m16 = lane & 15, q = lane >> 4;
        const unsigned short* U = (const unsigned short*)(lds + it * IT);
        const float* AT = &lds[it * IT + HLO];

        // A-frag: A[pos=m16][k=m] = h2[ch][pos]; h2bf hi us base 0, lo us base 792
        int kd = m16 >> 1, par = m16 & 1;
        union { unsigned u[4]; short8 v; } HA, LA;
#pragma unroll
        for (int i = 0; i < 4; ++i) {
            int ch = half * 32 + q * 8 + 2 * i;
            unsigned h0 = U[kd * 132 + ch * 2 + par];
            unsigned h1u = U[kd * 132 + (ch + 1) * 2 + par];
            unsigned l0 = U[792 + kd * 132 + ch * 2 + par];
            unsigned l1 = U[792 + kd * 132 + (ch + 1) * 2 + par];
            HA.u[i] = h0 | (h1u << 16);
            LA.u[i] = l0 | (l1 << 16);
        }
        // B-frags: att2 rows -> bf16 hi/lo via cvt_pk
        short8 bh[2], bl[2];
#pragma unroll
        for (int nt = 0; nt < 2; ++nt) {
            union { unsigned u[4]; short8 v; } H, L;
#pragma unroll
            for (int i = 0; i < 4; ++i) {
                int m = q * 8 + 2 * i;
                float a0 = AT[(half * 32 + m) * 33 + nt * 16 + m16];
                float a1 = AT[(half * 32 + m + 1) * 33 + nt * 16 + m16];
                unsigned hp, lp;
                hilo_pair(a0, a1, hp, lp);
                H.u[i] = hp; L.u[i] = lp;
            }
            bh[nt] = H.v; bl[nt] = L.v;
        }
        v4f zz = {0.f, 0.f, 0.f, 0.f};
        v4f acc[2]; acc[0] = zz; acc[1] = zz;
#pragma unroll
        for (int nt = 0; nt < 2; ++nt) {
            acc[nt] = __builtin_amdgcn_mfma_f32_16x16x32_bf16(HA.v, bh[nt], acc[nt], 0, 0, 0);
            acc[nt] = __builtin_amdgcn_mfma_f32_16x16x32_bf16(HA.v, bl[nt], acc[nt], 0, 0, 0);
            acc[nt] = __builtin_amdgcn_mfma_f32_16x16x32_bf16(LA.v, bh[nt], acc[nt], 0, 0, 0);
        }

        __syncthreads();   // all h2bf reads done before p2f overwrites [0,384)

        // epilogue: D[pos=q*4+r][n=nt*16+m16]
        if (q < 3) {
#pragma unroll
            for (int nt = 0; nt < 2; ++nt) {
                int n = nt * 16 + m16;
                float inv = cst[64 + n], sh = cst[96 + n];
#pragma unroll
                for (int rr = 0; rr < 2; ++rr) {
                    int j = q * 2 + rr;
                    float v0 = acc[nt][rr * 2] * inv + sh;
                    float v1 = acc[nt][rr * 2 + 1] * inv + sh;
                    lds[it * IT + n * 12 + half * 6 + j] =
                        fmaxf(fmaxf(v0, v1), 0.f);
                }
            }
        }
    }
    __syncthreads();

    // ---- phase 11: linear 384 -> 13, both items; float4 dot ----
    if (tid < 208) {
        int s8 = tid & 7;
        int rest = tid >> 3;
        int it = (rest >= 13) ? 1 : 0;
        int o = rest - it * 13;
        const float4* wv4 = (const float4*)(lw + o * 384 + s8 * 48);
        const float4* fv4 = (const float4*)&lds[it * IT + s8 * 48];
        float s = 0.f;
#pragma unroll
        for (int i = 0; i < 12; ++i) {
            float4 w4 = wv4[i];
            float4 f4 = fv4[i];
            s += f4.x * w4.x + f4.y * w4.y + f4.z * w4.z + f4.w * w4.w;
        }
        s += __shfl_down(s, 4, 8);
        s += __shfl_down(s, 2, 8);
        s += __shfl_down(s, 1, 8);
        if (s8 == 0) out[(size_t)(b0 + it) * 13 + o] = s + lb[o];
    }
}

extern "C" void kernel_launch(void* const* d_in, const int* in_sizes, int n_in,
                              void* d_out, int out_size, void* d_ws, size_t ws_size,
                              hipStream_t stream) {
    const float* x   = (const float*)d_in[0];
    const float* w1  = (const float*)d_in[1];
    const float* b1  = (const float*)d_in[2];
    const float* g1  = (const float*)d_in[3];
    const float* be1 = (const float*)d_in[4];
    const float* mu1 = (const float*)d_in[5];
    const float* va1 = (const float*)d_in[6];
    const float* w2  = (const float*)d_in[7];
    const float* b2  = (const float*)d_in[8];
    const float* g2  = (const float*)d_in[9];
    const float* be2 = (const float*)d_in[10];
    const float* mu2 = (const float*)d_in[11];
    const float* va2 = (const float*)d_in[12];
    const float* lw  = (const float*)d_in[13];
    const float* lb  = (const float*)d_in[14];
    float* out = (float*)d_out;
    unsigned short* ws16 = (unsigned short*)d_ws;

    // pack conv1 (kw-split) + conv2 weights into MFMA B-fragments, 64 KB in d_ws
    prep_kernel<<<8, 256, 0, stream>>>(w1, w2, ws16);

    int B = in_sizes[0] / 1250;  // 16384
    gcn_kernel<<<B / 2, 256, 0, stream>>>(x, w1, b1, g1, be1, mu1, va1,
                                          w2, b2, g2, be2, mu2, va2, lw, lb,
                                          ws16, out);
}